// Round 1
// baseline (900.638 us; speedup 1.0000x reference)
//
#include <hip/hip_runtime.h>
#include <hip/hip_bf16.h>
#include <math.h>

#define T_ 2048
#define H_ 1024
#define HQ_ 16
#define HK_ 4
#define D_ 64
#define NE_ 8
#define II_ 2048

typedef __attribute__((ext_vector_type(8))) short bf16x8;
typedef __attribute__((ext_vector_type(8))) unsigned short u16x8;
typedef __attribute__((ext_vector_type(4))) float f32x4;

__device__ __forceinline__ unsigned short f2bf(float f) {
  unsigned int u = __float_as_uint(f);
  return (unsigned short)((u + 0x7fffu + ((u >> 16) & 1u)) >> 16);
}

// ---------------- rmsnorm (fp32 in, fp32 out + optional bf16 out) ----------------
__global__ __launch_bounds__(256) void k_rmsnorm(const float* __restrict__ x, const float* __restrict__ w,
                                                 float* __restrict__ outf, unsigned short* __restrict__ outb) {
  int row = blockIdx.x;
  int tid = threadIdx.x;
  float4 v = ((const float4*)(x + (size_t)row * H_))[tid];
  float ss = v.x * v.x + v.y * v.y + v.z * v.z + v.w * v.w;
#pragma unroll
  for (int off = 32; off; off >>= 1) ss += __shfl_xor(ss, off, 64);
  __shared__ float red[4];
  int lane = tid & 63, wid = tid >> 6;
  if (lane == 0) red[wid] = ss;
  __syncthreads();
  float tot = red[0] + red[1] + red[2] + red[3];
  float inv = rsqrtf(tot * (1.0f / H_) + 1e-5f);
  float4 wv = ((const float4*)w)[tid];
  float4 o;
  o.x = v.x * inv * wv.x; o.y = v.y * inv * wv.y; o.z = v.z * inv * wv.z; o.w = v.w * inv * wv.w;
  ((float4*)(outf + (size_t)row * H_))[tid] = o;
  if (outb) {
    ushort4 b; b.x = f2bf(o.x); b.y = f2bf(o.y); b.z = f2bf(o.z); b.w = f2bf(o.w);
    ((ushort4*)(outb + (size_t)row * H_))[tid] = b;
  }
}

// ---------------- fp32 GEMM: C[M][N] = A[M][K] @ B[N][K]^T (+ optional add) ----------------
template <int ADD>
__global__ __launch_bounds__(256) void k_sgemm_nt(const float* __restrict__ A, const float* __restrict__ B,
                                                  float* __restrict__ C, const float* __restrict__ addsrc,
                                                  int M, int N, int K) {
  __shared__ float As[32 * 68];
  __shared__ float Bs[32 * 68];
  int m0 = blockIdx.y * 64, n0 = blockIdx.x * 64;
  int tid = threadIdx.x, tx = tid & 15, ty = tid >> 4;
  float acc[4][4];
#pragma unroll
  for (int i = 0; i < 4; i++)
#pragma unroll
    for (int j = 0; j < 4; j++) acc[i][j] = 0.f;

  for (int kb = 0; kb < K; kb += 32) {
    __syncthreads();
    for (int c = tid; c < 512; c += 256) {
      int row = c >> 3, kc = c & 7;
      float4 va = *(const float4*)(A + (size_t)(m0 + row) * K + kb + kc * 4);
      As[(kc * 4 + 0) * 68 + row] = va.x;
      As[(kc * 4 + 1) * 68 + row] = va.y;
      As[(kc * 4 + 2) * 68 + row] = va.z;
      As[(kc * 4 + 3) * 68 + row] = va.w;
      float4 vb = *(const float4*)(B + (size_t)(n0 + row) * K + kb + kc * 4);
      Bs[(kc * 4 + 0) * 68 + row] = vb.x;
      Bs[(kc * 4 + 1) * 68 + row] = vb.y;
      Bs[(kc * 4 + 2) * 68 + row] = vb.z;
      Bs[(kc * 4 + 3) * 68 + row] = vb.w;
    }
    __syncthreads();
#pragma unroll 16
    for (int kk = 0; kk < 32; ++kk) {
      float4 av = *(const float4*)&As[kk * 68 + ty * 4];
      float4 bv = *(const float4*)&Bs[kk * 68 + tx * 4];
      acc[0][0] += av.x * bv.x; acc[0][1] += av.x * bv.y; acc[0][2] += av.x * bv.z; acc[0][3] += av.x * bv.w;
      acc[1][0] += av.y * bv.x; acc[1][1] += av.y * bv.y; acc[1][2] += av.y * bv.z; acc[1][3] += av.y * bv.w;
      acc[2][0] += av.z * bv.x; acc[2][1] += av.z * bv.y; acc[2][2] += av.z * bv.z; acc[2][3] += av.z * bv.w;
      acc[3][0] += av.w * bv.x; acc[3][1] += av.w * bv.y; acc[3][2] += av.w * bv.z; acc[3][3] += av.w * bv.w;
    }
  }
#pragma unroll
  for (int i = 0; i < 4; i++) {
    size_t off = (size_t)(m0 + ty * 4 + i) * N + n0 + tx * 4;
    float4 o; o.x = acc[i][0]; o.y = acc[i][1]; o.z = acc[i][2]; o.w = acc[i][3];
    if (ADD) {
      float4 ad = *(const float4*)(addsrc + off);
      o.x += ad.x; o.y += ad.y; o.z += ad.z; o.w += ad.w;
    }
    *(float4*)(C + off) = o;
  }
}

// ---------------- RoPE cos/sin table (matches np float32 angle bits) ----------------
__global__ __launch_bounds__(256) void k_rope_table(const int* __restrict__ pos, float* __restrict__ ct,
                                                    float* __restrict__ st) {
  int idx = blockIdx.x * 256 + threadIdx.x;  // T*32
  int t = idx >> 5, i = idx & 31;
  float p = (float)pow(10000.0, (double)i / 32.0);
  float freq = 1.0f / p;
  float ang = (float)pos[t] * freq;
  ct[idx] = cosf(ang);
  st[idx] = sinf(ang);
}

// ---------------- RoPE apply + layout prep: Qr[h][t][d], Kt[h][d][t], Vv[h][t][d] ----------------
__global__ __launch_bounds__(256) void k_rope_prepare(const float* __restrict__ qkv, const float* __restrict__ ct,
                                                      const float* __restrict__ st, float* __restrict__ Qr,
                                                      float* __restrict__ Kt, float* __restrict__ Vv) {
  int t = blockIdx.x, tid = threadIdx.x;
  const float* row = qkv + (size_t)t * 1536;
  for (int it = tid; it < 512; it += 256) {
    int h = it >> 5, i = it & 31;
    float c = ct[t * 32 + i], s = st[t * 32 + i];
    float x1 = row[h * 64 + i], x2 = row[h * 64 + i + 32];
    Qr[((size_t)h * T_ + t) * 64 + i] = x1 * c - x2 * s;
    Qr[((size_t)h * T_ + t) * 64 + i + 32] = x2 * c + x1 * s;
  }
  if (tid < 128) {
    int h = tid >> 5, i = tid & 31;
    float c = ct[t * 32 + i], s = st[t * 32 + i];
    float x1 = row[1024 + h * 64 + i], x2 = row[1024 + h * 64 + i + 32];
    Kt[((size_t)(h * 64 + i)) * T_ + t] = x1 * c - x2 * s;
    Kt[((size_t)(h * 64 + i + 32)) * T_ + t] = x2 * c + x1 * s;
  }
  {
    int h = tid >> 6, d = tid & 63;
    Vv[((size_t)h * T_ + t) * 64 + d] = row[1280 + h * 64 + d];
  }
}

// ---------------- fp32 flash attention (causal, GQA 4:1), 64 q-rows per block ----------------
__global__ __launch_bounds__(256) void k_attn(const float* __restrict__ Qr, const float* __restrict__ Kt,
                                              const float* __restrict__ Vv, float* __restrict__ attnb) {
  int qb = blockIdx.x * 64;
  int head = blockIdx.y;
  int kvh = head >> 2;
  int tid = threadIdx.x;
  int tx = tid & 15, ty = tid >> 4;
  __shared__ float Qs[64 * 68];
  __shared__ float Ks[64 * 64];
  __shared__ float Vs[64 * 64];
  __shared__ float Ps[64 * 68];
  for (int c = tid; c < 1024; c += 256) {
    int r = c >> 4, d4 = (c & 15) * 4;
    float4 v = *(const float4*)(Qr + ((size_t)head * T_ + qb + r) * 64 + d4);
    Qs[r * 68 + d4 + 0] = v.x * 0.125f;
    Qs[r * 68 + d4 + 1] = v.y * 0.125f;
    Qs[r * 68 + d4 + 2] = v.z * 0.125f;
    Qs[r * 68 + d4 + 3] = v.w * 0.125f;
  }
  float O[4][4];
  float mrow[4], lrow[4];
#pragma unroll
  for (int qi = 0; qi < 4; qi++) {
    mrow[qi] = -1e30f; lrow[qi] = 0.f;
#pragma unroll
    for (int di = 0; di < 4; di++) O[qi][di] = 0.f;
  }
  for (int jb = 0; jb <= qb; jb += 64) {
    __syncthreads();
    for (int c = tid; c < 1024; c += 256) {
      int r = c >> 4, j4 = (c & 15) * 4;
      *(float4*)&Ks[r * 64 + j4] = *(const float4*)(Kt + ((size_t)(kvh * 64 + r)) * T_ + jb + j4);
      *(float4*)&Vs[r * 64 + j4] = *(const float4*)(Vv + ((size_t)kvh * T_ + jb + r) * 64 + j4);
    }
    __syncthreads();
    float sc[4][4];
#pragma unroll
    for (int qi = 0; qi < 4; qi++)
#pragma unroll
      for (int ki = 0; ki < 4; ki++) sc[qi][ki] = 0.f;
#pragma unroll 16
    for (int d = 0; d < 64; ++d) {
      float4 kv4 = *(const float4*)&Ks[d * 64 + tx * 4];
      float q0 = Qs[(ty * 4 + 0) * 68 + d];
      float q1 = Qs[(ty * 4 + 1) * 68 + d];
      float q2 = Qs[(ty * 4 + 2) * 68 + d];
      float q3 = Qs[(ty * 4 + 3) * 68 + d];
      sc[0][0] += q0 * kv4.x; sc[0][1] += q0 * kv4.y; sc[0][2] += q0 * kv4.z; sc[0][3] += q0 * kv4.w;
      sc[1][0] += q1 * kv4.x; sc[1][1] += q1 * kv4.y; sc[1][2] += q1 * kv4.z; sc[1][3] += q1 * kv4.w;
      sc[2][0] += q2 * kv4.x; sc[2][1] += q2 * kv4.y; sc[2][2] += q2 * kv4.z; sc[2][3] += q2 * kv4.w;
      sc[3][0] += q3 * kv4.x; sc[3][1] += q3 * kv4.y; sc[3][2] += q3 * kv4.z; sc[3][3] += q3 * kv4.w;
    }
    if (jb == qb) {
#pragma unroll
      for (int qi = 0; qi < 4; qi++)
#pragma unroll
        for (int ki = 0; ki < 4; ki++)
          if (tx * 4 + ki > ty * 4 + qi) sc[qi][ki] = -1e30f;
    }
#pragma unroll
    for (int qi = 0; qi < 4; qi++) {
      float mt = fmaxf(fmaxf(sc[qi][0], sc[qi][1]), fmaxf(sc[qi][2], sc[qi][3]));
      mt = fmaxf(mt, __shfl_xor(mt, 1, 64));
      mt = fmaxf(mt, __shfl_xor(mt, 2, 64));
      mt = fmaxf(mt, __shfl_xor(mt, 4, 64));
      mt = fmaxf(mt, __shfl_xor(mt, 8, 64));
      float mnew = fmaxf(mrow[qi], mt);
      float corr = expf(mrow[qi] - mnew);
      mrow[qi] = mnew;
      float ps = 0.f;
#pragma unroll
      for (int ki = 0; ki < 4; ki++) {
        float pp = expf(sc[qi][ki] - mnew);
        sc[qi][ki] = pp;
        ps += pp;
      }
      ps += __shfl_xor(ps, 1, 64);
      ps += __shfl_xor(ps, 2, 64);
      ps += __shfl_xor(ps, 4, 64);
      ps += __shfl_xor(ps, 8, 64);
      lrow[qi] = lrow[qi] * corr + ps;
#pragma unroll
      for (int di = 0; di < 4; di++) O[qi][di] *= corr;
      float4 pv; pv.x = sc[qi][0]; pv.y = sc[qi][1]; pv.z = sc[qi][2]; pv.w = sc[qi][3];
      *(float4*)&Ps[(ty * 4 + qi) * 68 + tx * 4] = pv;  // same-wave producer/consumer: no barrier needed
    }
#pragma unroll 16
    for (int j = 0; j < 64; ++j) {
      float4 vv = *(const float4*)&Vs[j * 64 + tx * 4];
      float p0 = Ps[(ty * 4 + 0) * 68 + j];
      float p1 = Ps[(ty * 4 + 1) * 68 + j];
      float p2 = Ps[(ty * 4 + 2) * 68 + j];
      float p3 = Ps[(ty * 4 + 3) * 68 + j];
      O[0][0] += p0 * vv.x; O[0][1] += p0 * vv.y; O[0][2] += p0 * vv.z; O[0][3] += p0 * vv.w;
      O[1][0] += p1 * vv.x; O[1][1] += p1 * vv.y; O[1][2] += p1 * vv.z; O[1][3] += p1 * vv.w;
      O[2][0] += p2 * vv.x; O[2][1] += p2 * vv.y; O[2][2] += p2 * vv.z; O[2][3] += p2 * vv.w;
      O[3][0] += p3 * vv.x; O[3][1] += p3 * vv.y; O[3][2] += p3 * vv.z; O[3][3] += p3 * vv.w;
    }
  }
#pragma unroll
  for (int qi = 0; qi < 4; qi++) {
    float inv = 1.0f / lrow[qi];
    float4 o;
    o.x = O[qi][0] * inv; o.y = O[qi][1] * inv; o.z = O[qi][2] * inv; o.w = O[qi][3] * inv;
    *(float4*)(attnb + (size_t)(qb + ty * 4 + qi) * (HQ_ * D_) + head * 64 + tx * 4) = o;
  }
}

// ---------------- router: logits, top-2, weights, expert counts ----------------
__global__ __launch_bounds__(256) void k_router(const float* __restrict__ h2, const float* __restrict__ gw,
                                                int* __restrict__ topi, float* __restrict__ topw,
                                                int* __restrict__ counts) {
  int wid = threadIdx.x >> 6, lane = threadIdx.x & 63;
  int t = blockIdx.x * 4 + wid;
  const float* hr = h2 + (size_t)t * H_;
  float hv[16];
#pragma unroll
  for (int i = 0; i < 16; i++) hv[i] = hr[lane + 64 * i];
  float le[8];
#pragma unroll
  for (int e = 0; e < 8; e++) {
    const float* g = gw + (size_t)e * H_;
    float acc = 0.f;
#pragma unroll
    for (int i = 0; i < 16; i++) acc += hv[i] * g[lane + 64 * i];
#pragma unroll
    for (int off = 32; off; off >>= 1) acc += __shfl_xor(acc, off, 64);
    le[e] = acc;
  }
  if (lane == 0) {
    int i0 = 0;
#pragma unroll
    for (int e = 1; e < 8; e++)
      if (le[e] > le[i0]) i0 = e;
    int i1 = (i0 == 0) ? 1 : 0;
#pragma unroll
    for (int e = 0; e < 8; e++) {
      if (e == i0) continue;
      if (le[e] > le[i1]) i1 = e;
    }
    float w1r = expf(le[i1] - le[i0]);
    float denom = 1.0f + w1r;
    topi[t * 2 + 0] = i0;
    topi[t * 2 + 1] = i1;
    topw[t * 2 + 0] = 1.0f / denom;
    topw[t * 2 + 1] = w1r / denom;
    atomicAdd(&counts[i0], 1);
    atomicAdd(&counts[i1], 1);
  }
}

__global__ void k_scan(const int* __restrict__ counts, int* __restrict__ offsets) {
  if (threadIdx.x == 0 && blockIdx.x == 0) {
    int off = 0;
    for (int e = 0; e < NE_; e++) { offsets[e] = off; off += counts[e]; }
  }
}

__global__ __launch_bounds__(256) void k_build(const int* __restrict__ topi, const float* __restrict__ topw,
                                               const int* __restrict__ offsets, int* __restrict__ counts2,
                                               int* __restrict__ pairs_ts, float* __restrict__ pairs_w) {
  int t = blockIdx.x * 256 + threadIdx.x;
#pragma unroll
  for (int s = 0; s < 2; s++) {
    int e = topi[t * 2 + s];
    int slot = atomicAdd(&counts2[e], 1);
    int p = offsets[e] + slot;
    pairs_ts[p] = t * 2 + s;
    pairs_w[p] = topw[t * 2 + s];
  }
}

// ---------------- MoE up: gated = silu(A@w1^T) * (A@w3^T), bf16 MFMA ----------------
__global__ __launch_bounds__(256) void k_moe_up(const unsigned short* __restrict__ h2b, const float* __restrict__ w1,
                                                const float* __restrict__ w3, const int* __restrict__ pairs_ts,
                                                const int* __restrict__ offsets, const int* __restrict__ counts,
                                                unsigned short* __restrict__ G) {
  int e = blockIdx.z;
  int ne = counts[e];
  int row0 = blockIdx.y * 128;
  if (row0 >= ne) return;
  int col0 = blockIdx.x * 64;
  int pbase = offsets[e];
  __shared__ unsigned short As[128 * 32];
  __shared__ unsigned short B1s[64 * 32];
  __shared__ unsigned short B2s[64 * 32];
  int tid = threadIdx.x, lane = tid & 63, wid = tid >> 6;
  int wr = wid >> 1, wc = wid & 1;
  f32x4 acc1[4][2], acc2[4][2];
  f32x4 z = {0.f, 0.f, 0.f, 0.f};
#pragma unroll
  for (int a = 0; a < 4; a++)
#pragma unroll
    for (int b = 0; b < 2; b++) { acc1[a][b] = z; acc2[a][b] = z; }

  for (int kb = 0; kb < H_; kb += 32) {
    __syncthreads();
    for (int c = tid; c < 512; c += 256) {
      int row = c >> 2, k16 = c & 3;
      int grow = row0 + row;
      int tok = (grow < ne) ? (pairs_ts[pbase + grow] >> 1) : 0;
      *(uint4*)&As[row * 32 + k16 * 8] = *(const uint4*)(h2b + (size_t)tok * H_ + kb + k16 * 8);
    }
    {
      int n = tid >> 2, k16 = tid & 3;
      const float* s1 = w1 + ((size_t)e * II_ + col0 + n) * H_ + kb + k16 * 8;
      float4 a = *(const float4*)s1;
      float4 b = *(const float4*)(s1 + 4);
      u16x8 t1;
      t1[0] = f2bf(a.x); t1[1] = f2bf(a.y); t1[2] = f2bf(a.z); t1[3] = f2bf(a.w);
      t1[4] = f2bf(b.x); t1[5] = f2bf(b.y); t1[6] = f2bf(b.z); t1[7] = f2bf(b.w);
      *(u16x8*)&B1s[n * 32 + k16 * 8] = t1;
      const float* s3 = w3 + ((size_t)e * II_ + col0 + n) * H_ + kb + k16 * 8;
      float4 a3 = *(const float4*)s3;
      float4 b3 = *(const float4*)(s3 + 4);
      u16x8 t3;
      t3[0] = f2bf(a3.x); t3[1] = f2bf(a3.y); t3[2] = f2bf(a3.z); t3[3] = f2bf(a3.w);
      t3[4] = f2bf(b3.x); t3[5] = f2bf(b3.y); t3[6] = f2bf(b3.z); t3[7] = f2bf(b3.w);
      *(u16x8*)&B2s[n * 32 + k16 * 8] = t3;
    }
    __syncthreads();
    bf16x8 af[4], b1f[2], b2f[2];
#pragma unroll
    for (int fa = 0; fa < 4; fa++)
      af[fa] = *(const bf16x8*)&As[(wr * 64 + fa * 16 + (lane & 15)) * 32 + (lane >> 4) * 8];
#pragma unroll
    for (int fb = 0; fb < 2; fb++) {
      b1f[fb] = *(const bf16x8*)&B1s[(wc * 32 + fb * 16 + (lane & 15)) * 32 + (lane >> 4) * 8];
      b2f[fb] = *(const bf16x8*)&B2s[(wc * 32 + fb * 16 + (lane & 15)) * 32 + (lane >> 4) * 8];
    }
#pragma unroll
    for (int fa = 0; fa < 4; fa++)
#pragma unroll
      for (int fb = 0; fb < 2; fb++) {
        acc1[fa][fb] = __builtin_amdgcn_mfma_f32_16x16x32_bf16(af[fa], b1f[fb], acc1[fa][fb], 0, 0, 0);
        acc2[fa][fb] = __builtin_amdgcn_mfma_f32_16x16x32_bf16(af[fa], b2f[fb], acc2[fa][fb], 0, 0, 0);
      }
  }
#pragma unroll
  for (int fa = 0; fa < 4; fa++)
#pragma unroll
    for (int fb = 0; fb < 2; fb++)
#pragma unroll
      for (int r = 0; r < 4; r++) {
        int prow = row0 + wr * 64 + fa * 16 + (lane >> 4) * 4 + r;
        if (prow < ne) {
          int icol = col0 + wc * 32 + fb * 16 + (lane & 15);
          float h1 = acc1[fa][fb][r], h3 = acc2[fa][fb][r];
          float g = h1 / (1.0f + __expf(-h1)) * h3;
          G[(size_t)(pbase + prow) * II_ + icol] = f2bf(g);
        }
      }
}

// ---------------- MoE down: P[t][s] = w * (G @ w2^T), bf16 MFMA ----------------
__global__ __launch_bounds__(256) void k_moe_down(const unsigned short* __restrict__ G, const float* __restrict__ w2,
                                                  const int* __restrict__ pairs_ts, const float* __restrict__ pairs_w,
                                                  const int* __restrict__ offsets, const int* __restrict__ counts,
                                                  float* __restrict__ Pbuf) {
  int e = blockIdx.z;
  int ne = counts[e];
  int row0 = blockIdx.y * 128;
  if (row0 >= ne) return;
  int col0 = blockIdx.x * 128;
  int pbase = offsets[e];
  __shared__ unsigned short As[128 * 32];
  __shared__ unsigned short Bs[128 * 32];
  int tid = threadIdx.x, lane = tid & 63, wid = tid >> 6;
  int wr = wid >> 1, wc = wid & 1;
  f32x4 acc[4][4];
  f32x4 z = {0.f, 0.f, 0.f, 0.f};
#pragma unroll
  for (int a = 0; a < 4; a++)
#pragma unroll
    for (int b = 0; b < 4; b++) acc[a][b] = z;

  for (int kb = 0; kb < II_; kb += 32) {
    __syncthreads();
    for (int c = tid; c < 512; c += 256) {
      int row = c >> 2, k16 = c & 3;
      int grow = row0 + row;
      size_t p = (size_t)pbase + ((grow < ne) ? grow : 0);
      *(uint4*)&As[row * 32 + k16 * 8] = *(const uint4*)(G + p * II_ + kb + k16 * 8);
    }
    for (int c = tid; c < 512; c += 256) {
      int n = c >> 2, k16 = c & 3;
      const float* s = w2 + ((size_t)e * H_ + col0 + n) * II_ + kb + k16 * 8;
      float4 a = *(const float4*)s;
      float4 b = *(const float4*)(s + 4);
      u16x8 tv;
      tv[0] = f2bf(a.x); tv[1] = f2bf(a.y); tv[2] = f2bf(a.z); tv[3] = f2bf(a.w);
      tv[4] = f2bf(b.x); tv[5] = f2bf(b.y); tv[6] = f2bf(b.z); tv[7] = f2bf(b.w);
      *(u16x8*)&Bs[n * 32 + k16 * 8] = tv;
    }
    __syncthreads();
    bf16x8 af[4], bf[4];
#pragma unroll
    for (int fa = 0; fa < 4; fa++)
      af[fa] = *(const bf16x8*)&As[(wr * 64 + fa * 16 + (lane & 15)) * 32 + (lane >> 4) * 8];
#pragma unroll
    for (int fb = 0; fb < 4; fb++)
      bf[fb] = *(const bf16x8*)&Bs[(wc * 64 + fb * 16 + (lane & 15)) * 32 + (lane >> 4) * 8];
#pragma unroll
    for (int fa = 0; fa < 4; fa++)
#pragma unroll
      for (int fb = 0; fb < 4; fb++)
        acc[fa][fb] = __builtin_amdgcn_mfma_f32_16x16x32_bf16(af[fa], bf[fb], acc[fa][fb], 0, 0, 0);
  }
#pragma unroll
  for (int fa = 0; fa < 4; fa++)
#pragma unroll
    for (int fb = 0; fb < 4; fb++)
#pragma unroll
      for (int r = 0; r < 4; r++) {
        int prow = row0 + wr * 64 + fa * 16 + (lane >> 4) * 4 + r;
        if (prow < ne) {
          int p = pbase + prow;
          int ts = pairs_ts[p];
          float wgt = pairs_w[p];
          int col = col0 + wc * 64 + fb * 16 + (lane & 15);
          Pbuf[(size_t)ts * H_ + col] = wgt * acc[fa][fb][r];
        }
      }
}

// ---------------- final: out = rmsnorm(resid + P0 + P1) ----------------
__global__ __launch_bounds__(256) void k_final(const float* __restrict__ resid, const float* __restrict__ Pbuf,
                                               const float* __restrict__ w, float* __restrict__ out) {
  int row = blockIdx.x;
  int tid = threadIdx.x;
  float4 a = ((const float4*)(resid + (size_t)row * H_))[tid];
  float4 p0 = ((const float4*)(Pbuf + (size_t)(2 * row) * H_))[tid];
  float4 p1 = ((const float4*)(Pbuf + (size_t)(2 * row + 1) * H_))[tid];
  float4 v;
  v.x = a.x + p0.x + p1.x; v.y = a.y + p0.y + p1.y; v.z = a.z + p0.z + p1.z; v.w = a.w + p0.w + p1.w;
  float ss = v.x * v.x + v.y * v.y + v.z * v.z + v.w * v.w;
#pragma unroll
  for (int off = 32; off; off >>= 1) ss += __shfl_xor(ss, off, 64);
  __shared__ float red[4];
  int lane = tid & 63, wid = tid >> 6;
  if (lane == 0) red[wid] = ss;
  __syncthreads();
  float tot = red[0] + red[1] + red[2] + red[3];
  float inv = rsqrtf(tot * (1.0f / H_) + 1e-5f);
  float4 wv = ((const float4*)w)[tid];
  float4 o;
  o.x = v.x * inv * wv.x; o.y = v.y * inv * wv.y; o.z = v.z * inv * wv.z; o.w = v.w * inv * wv.w;
  ((float4*)(out + (size_t)row * H_))[tid] = o;
}

extern "C" void kernel_launch(void* const* d_in, const int* in_sizes, int n_in,
                              void* d_out, int out_size, void* d_ws, size_t ws_size,
                              hipStream_t stream) {
  const float* x = (const float*)d_in[0];
  const int* pos = (const int*)d_in[1];
  const float* qkv_w = (const float*)d_in[2];
  const float* o_w = (const float*)d_in[3];
  const float* nin_w = (const float*)d_in[4];
  const float* npost_w = (const float*)d_in[5];
  const float* nnext_w = (const float*)d_in[6];
  const float* gate_w = (const float*)d_in[7];
  const float* w1 = (const float*)d_in[8];
  const float* w3 = (const float*)d_in[9];
  const float* w2 = (const float*)d_in[10];
  float* out = (float*)d_out;

  float* f = (float*)d_ws;
  float* h_in = f;   f += (size_t)T_ * H_;
  float* qkvb = f;   f += (size_t)T_ * (HQ_ + 2 * HK_) * D_;
  float* Qr = f;     f += (size_t)HQ_ * T_ * D_;
  float* Ktp = f;    f += (size_t)HK_ * D_ * T_;
  float* Vv = f;     f += (size_t)HK_ * T_ * D_;
  float* attnb = f;  f += (size_t)T_ * HQ_ * D_;
  float* resid = f;  f += (size_t)T_ * H_;
  float* h2 = f;     f += (size_t)T_ * H_;
  float* ct = f;     f += (size_t)T_ * 32;
  float* st = f;     f += (size_t)T_ * 32;
  float* topw = f;   f += (size_t)T_ * 2;
  float* pairsw = f; f += 4096;
  float* Pbuf = f;   f += (size_t)T_ * 2 * H_;
  unsigned short* h2b = (unsigned short*)f;
  unsigned short* G = h2b + (size_t)T_ * H_;
  int* topi = (int*)(G + (size_t)2 * T_ * II_);
  int* ctrl = topi + T_ * 2;
  int* counts = ctrl;
  int* counts2 = ctrl + 8;
  int* offsets = ctrl + 16;
  int* pairs_ts = ctrl + 24;

  hipMemsetAsync(ctrl, 0, 64, stream);  // counts + counts2
  k_rmsnorm<<<T_, 256, 0, stream>>>(x, nin_w, h_in, (unsigned short*)nullptr);
  k_sgemm_nt<0><<<dim3((HQ_ + 2 * HK_) * D_ / 64, T_ / 64), 256, 0, stream>>>(h_in, qkv_w, qkvb, nullptr, T_,
                                                                              (HQ_ + 2 * HK_) * D_, H_);
  k_rope_table<<<T_ * 32 / 256, 256, 0, stream>>>(pos, ct, st);
  k_rope_prepare<<<T_, 256, 0, stream>>>(qkvb, ct, st, Qr, Ktp, Vv);
  k_attn<<<dim3(T_ / 64, HQ_), 256, 0, stream>>>(Qr, Ktp, Vv, attnb);
  k_sgemm_nt<1><<<dim3(H_ / 64, T_ / 64), 256, 0, stream>>>(attnb, o_w, resid, x, T_, H_, HQ_ * D_);
  k_rmsnorm<<<T_, 256, 0, stream>>>(resid, npost_w, h2, h2b);
  k_router<<<T_ / 4, 256, 0, stream>>>(h2, gate_w, topi, topw, counts);
  k_scan<<<1, 64, 0, stream>>>(counts, offsets);
  k_build<<<T_ / 256, 256, 0, stream>>>(topi, topw, offsets, counts2, pairs_ts, pairsw);
  k_moe_up<<<dim3(II_ / 64, T_ / 128, NE_), 256, 0, stream>>>(h2b, w1, w3, pairs_ts, offsets, counts, G);
  k_moe_down<<<dim3(H_ / 128, T_ / 128, NE_), 256, 0, stream>>>(G, w2, pairs_ts, pairsw, offsets, counts, Pbuf);
  k_final<<<T_, 256, 0, stream>>>(resid, Pbuf, nnext_w, out);
}

// Round 3
// 706.529 us; speedup vs baseline: 1.2747x; 1.2747x over previous
//
#include <hip/hip_runtime.h>
#include <hip/hip_bf16.h>
#include <math.h>

#define T_ 2048
#define H_ 1024
#define HQ_ 16
#define HK_ 4
#define D_ 64
#define NE_ 8
#define II_ 2048

typedef __attribute__((ext_vector_type(8))) short bf16x8;
typedef __attribute__((ext_vector_type(8))) unsigned short u16x8;
typedef __attribute__((ext_vector_type(4))) float f32x4;

__device__ __forceinline__ unsigned short f2bf(float f) {
  unsigned int u = __float_as_uint(f);
  return (unsigned short)((u + 0x7fffu + ((u >> 16) & 1u)) >> 16);
}
__device__ __forceinline__ float bf2f(unsigned short h) {
  return __uint_as_float((unsigned int)h << 16);
}

// ---------------- rmsnorm (fp32 in, fp32 out + optional bf16 out) ----------------
__global__ __launch_bounds__(256) void k_rmsnorm(const float* __restrict__ x, const float* __restrict__ w,
                                                 float* __restrict__ outf, unsigned short* __restrict__ outb) {
  int row = blockIdx.x;
  int tid = threadIdx.x;
  float4 v = ((const float4*)(x + (size_t)row * H_))[tid];
  float ss = v.x * v.x + v.y * v.y + v.z * v.z + v.w * v.w;
#pragma unroll
  for (int off = 32; off; off >>= 1) ss += __shfl_xor(ss, off, 64);
  __shared__ float red[4];
  int lane = tid & 63, wid = tid >> 6;
  if (lane == 0) red[wid] = ss;
  __syncthreads();
  float tot = red[0] + red[1] + red[2] + red[3];
  float inv = rsqrtf(tot * (1.0f / H_) + 1e-5f);
  float4 wv = ((const float4*)w)[tid];
  float4 o;
  o.x = v.x * inv * wv.x; o.y = v.y * inv * wv.y; o.z = v.z * inv * wv.z; o.w = v.w * inv * wv.w;
  ((float4*)(outf + (size_t)row * H_))[tid] = o;
  if (outb) {
    ushort4 b; b.x = f2bf(o.x); b.y = f2bf(o.y); b.z = f2bf(o.z); b.w = f2bf(o.w);
    ((ushort4*)(outb + (size_t)row * H_))[tid] = b;
  }
}

// ---------------- fp32 GEMM: C[M][N] = A[M][K] @ B[N][K]^T (+ optional add) ----------------
template <int ADD>
__global__ __launch_bounds__(256) void k_sgemm_nt(const float* __restrict__ A, const float* __restrict__ B,
                                                  float* __restrict__ C, const float* __restrict__ addsrc,
                                                  int M, int N, int K) {
  __shared__ float As[32 * 68];
  __shared__ float Bs[32 * 68];
  int m0 = blockIdx.y * 64, n0 = blockIdx.x * 64;
  int tid = threadIdx.x, tx = tid & 15, ty = tid >> 4;
  float acc[4][4];
#pragma unroll
  for (int i = 0; i < 4; i++)
#pragma unroll
    for (int j = 0; j < 4; j++) acc[i][j] = 0.f;

  for (int kb = 0; kb < K; kb += 32) {
    __syncthreads();
    for (int c = tid; c < 512; c += 256) {
      int row = c >> 3, kc = c & 7;
      float4 va = *(const float4*)(A + (size_t)(m0 + row) * K + kb + kc * 4);
      As[(kc * 4 + 0) * 68 + row] = va.x;
      As[(kc * 4 + 1) * 68 + row] = va.y;
      As[(kc * 4 + 2) * 68 + row] = va.z;
      As[(kc * 4 + 3) * 68 + row] = va.w;
      float4 vb = *(const float4*)(B + (size_t)(n0 + row) * K + kb + kc * 4);
      Bs[(kc * 4 + 0) * 68 + row] = vb.x;
      Bs[(kc * 4 + 1) * 68 + row] = vb.y;
      Bs[(kc * 4 + 2) * 68 + row] = vb.z;
      Bs[(kc * 4 + 3) * 68 + row] = vb.w;
    }
    __syncthreads();
#pragma unroll 16
    for (int kk = 0; kk < 32; ++kk) {
      float4 av = *(const float4*)&As[kk * 68 + ty * 4];
      float4 bv = *(const float4*)&Bs[kk * 68 + tx * 4];
      acc[0][0] += av.x * bv.x; acc[0][1] += av.x * bv.y; acc[0][2] += av.x * bv.z; acc[0][3] += av.x * bv.w;
      acc[1][0] += av.y * bv.x; acc[1][1] += av.y * bv.y; acc[1][2] += av.y * bv.z; acc[1][3] += av.y * bv.w;
      acc[2][0] += av.z * bv.x; acc[2][1] += av.z * bv.y; acc[2][2] += av.z * bv.z; acc[2][3] += av.z * bv.w;
      acc[3][0] += av.w * bv.x; acc[3][1] += av.w * bv.y; acc[3][2] += av.w * bv.z; acc[3][3] += av.w * bv.w;
    }
  }
#pragma unroll
  for (int i = 0; i < 4; i++) {
    size_t off = (size_t)(m0 + ty * 4 + i) * N + n0 + tx * 4;
    float4 o; o.x = acc[i][0]; o.y = acc[i][1]; o.z = acc[i][2]; o.w = acc[i][3];
    if (ADD) {
      float4 ad = *(const float4*)(addsrc + off);
      o.x += ad.x; o.y += ad.y; o.z += ad.z; o.w += ad.w;
    }
    *(float4*)(C + off) = o;
  }
}

// ---------------- RoPE cos/sin table (matches np float32 angle bits) ----------------
__global__ __launch_bounds__(256) void k_rope_table(const int* __restrict__ pos, float* __restrict__ ct,
                                                    float* __restrict__ st) {
  int idx = blockIdx.x * 256 + threadIdx.x;  // T*32
  int t = idx >> 5, i = idx & 31;
  float p = (float)pow(10000.0, (double)i / 32.0);
  float freq = 1.0f / p;
  float ang = (float)pos[t] * freq;
  ct[idx] = cosf(ang);
  st[idx] = sinf(ang);
}

// ---------------- RoPE apply + bf16 hi/lo split: Qhi/Qlo [h][t][d] (x0.125), Khi/Klo [kvh][t][d] ----------------
__global__ __launch_bounds__(256) void k_rope_prep(const float* __restrict__ qkv, const float* __restrict__ ct,
                                                   const float* __restrict__ st, unsigned short* __restrict__ Qhi,
                                                   unsigned short* __restrict__ Qlo, unsigned short* __restrict__ Khi,
                                                   unsigned short* __restrict__ Klo) {
  int t = blockIdx.x, tid = threadIdx.x;
  const float* row = qkv + (size_t)t * 1536;
#pragma unroll 2
  for (int it = tid; it < 512; it += 256) {
    int h = it >> 5, i = it & 31;
    float c = ct[t * 32 + i], s = st[t * 32 + i];
    float x1 = row[h * 64 + i], x2 = row[h * 64 + i + 32];
    float a = (x1 * c - x2 * s) * 0.125f;
    float b = (x2 * c + x1 * s) * 0.125f;
    size_t base = ((size_t)h * T_ + t) * 64 + i;
    unsigned short ah = f2bf(a), bh = f2bf(b);
    Qhi[base] = ah; Qhi[base + 32] = bh;
    Qlo[base] = f2bf(a - bf2f(ah));
    Qlo[base + 32] = f2bf(b - bf2f(bh));
  }
  if (tid < 128) {
    int h = tid >> 5, i = tid & 31;
    float c = ct[t * 32 + i], s = st[t * 32 + i];
    float x1 = row[1024 + h * 64 + i], x2 = row[1024 + h * 64 + i + 32];
    float a = x1 * c - x2 * s;
    float b = x2 * c + x1 * s;
    size_t base = ((size_t)h * T_ + t) * 64 + i;
    unsigned short ah = f2bf(a), bh = f2bf(b);
    Khi[base] = ah; Khi[base + 32] = bh;
    Klo[base] = f2bf(a - bf2f(ah));
    Klo[base + 32] = f2bf(b - bf2f(bh));
  }
}

// ---------------- V transpose + split: Vthi/Vtlo [kvh][d][t] ----------------
__global__ __launch_bounds__(256) void k_vtrans(const float* __restrict__ qkv, unsigned short* __restrict__ Vthi,
                                                unsigned short* __restrict__ Vtlo) {
  int t0 = blockIdx.x * 64, h = blockIdx.y;
  __shared__ float tile[64][65];
  int tid = threadIdx.x;
  int c = tid & 63, w = tid >> 6;
  for (int r = w; r < 64; r += 4)
    tile[r][c] = qkv[(size_t)(t0 + r) * 1536 + 1280 + h * 64 + c];
  __syncthreads();
  for (int d = w; d < 64; d += 4) {
    float v = tile[c][d];
    unsigned short hi = f2bf(v);
    size_t idx = ((size_t)h * 64 + d) * T_ + t0 + c;
    Vthi[idx] = hi;
    Vtlo[idx] = f2bf(v - bf2f(hi));
  }
}

// ---------------- flash attention, bf16x3 split MFMA (fp32-grade precision) ----------------
__global__ __launch_bounds__(256) void k_attn_mfma(const unsigned short* __restrict__ Qhi,
                                                   const unsigned short* __restrict__ Qlo,
                                                   const unsigned short* __restrict__ Khi,
                                                   const unsigned short* __restrict__ Klo,
                                                   const unsigned short* __restrict__ Vthi,
                                                   const unsigned short* __restrict__ Vtlo,
                                                   float* __restrict__ attnb) {
  int bid = blockIdx.x;
  int kk = bid >> 4;
  int head = bid & 15;
  // heavy-first + paired ordering: qidx 31..16 first, then 0..15 (co-resident pairs sum ~constant)
  int qidx = (kk < 16) ? (31 - kk) : (kk - 16);
  int qb = qidx * 64;
  int kvh = head >> 2;
  int tid = threadIdx.x, lane = tid & 63, w = tid >> 6;
  int l15 = lane & 15, lg = lane >> 4;

  // padded stride 72 shorts (144B): 16B-aligned b128 reads, optimal 8-lane bank spread
  __shared__ unsigned short KsH[64 * 72], KsL[64 * 72];
  __shared__ unsigned short VsH[64 * 72], VsL[64 * 72];  // V^T: row=d, col=key
  __shared__ unsigned short PsH[64 * 72], PsL[64 * 72];

  bf16x8 qh[2], ql[2];
  {
    size_t qbase = ((size_t)head * T_ + qb + w * 16 + l15) * 64 + lg * 8;
    qh[0] = *(const bf16x8*)(Qhi + qbase);
    qh[1] = *(const bf16x8*)(Qhi + qbase + 32);
    ql[0] = *(const bf16x8*)(Qlo + qbase);
    ql[1] = *(const bf16x8*)(Qlo + qbase + 32);
  }
  f32x4 z = {0.f, 0.f, 0.f, 0.f};
  f32x4 Oa[4];
  float mrow[4], lrow[4];
#pragma unroll
  for (int r = 0; r < 4; r++) { mrow[r] = -1e30f; lrow[r] = 0.f; }
#pragma unroll
  for (int dg = 0; dg < 4; dg++) Oa[dg] = z;

  for (int jb = 0; jb <= qb; jb += 64) {
    __syncthreads();
    for (int c = tid; c < 512; c += 256) {
      int r = c >> 3, g = (c & 7) * 8;
      size_t kgl = ((size_t)kvh * T_ + jb + r) * 64 + g;
      size_t vgl = ((size_t)kvh * 64 + r) * T_ + jb + g;
      *(uint4*)&KsH[r * 72 + g] = *(const uint4*)(Khi + kgl);
      *(uint4*)&KsL[r * 72 + g] = *(const uint4*)(Klo + kgl);
      *(uint4*)&VsH[r * 72 + g] = *(const uint4*)(Vthi + vgl);
      *(uint4*)&VsL[r * 72 + g] = *(const uint4*)(Vtlo + vgl);
    }
    __syncthreads();

    f32x4 sc[4];
    sc[0] = z; sc[1] = z; sc[2] = z; sc[3] = z;
#pragma unroll
    for (int kg = 0; kg < 4; kg++) {
      int ba = (kg * 16 + l15) * 72 + lg * 8;
      bf16x8 bh0 = *(const bf16x8*)&KsH[ba];
      bf16x8 bh1 = *(const bf16x8*)&KsH[ba + 32];
      bf16x8 bl0 = *(const bf16x8*)&KsL[ba];
      bf16x8 bl1 = *(const bf16x8*)&KsL[ba + 32];
      sc[kg] = __builtin_amdgcn_mfma_f32_16x16x32_bf16(qh[0], bh0, sc[kg], 0, 0, 0);
      sc[kg] = __builtin_amdgcn_mfma_f32_16x16x32_bf16(qh[1], bh1, sc[kg], 0, 0, 0);
      sc[kg] = __builtin_amdgcn_mfma_f32_16x16x32_bf16(qh[0], bl0, sc[kg], 0, 0, 0);
      sc[kg] = __builtin_amdgcn_mfma_f32_16x16x32_bf16(qh[1], bl1, sc[kg], 0, 0, 0);
      sc[kg] = __builtin_amdgcn_mfma_f32_16x16x32_bf16(ql[0], bh0, sc[kg], 0, 0, 0);
      sc[kg] = __builtin_amdgcn_mfma_f32_16x16x32_bf16(ql[1], bh1, sc[kg], 0, 0, 0);
    }
    if (jb == qb) {
      int rb = w * 16 + lg * 4;
#pragma unroll
      for (int kg = 0; kg < 4; kg++) {
        int col = kg * 16 + l15;
#pragma unroll
        for (int r = 0; r < 4; r++)
          if (col > rb + r) sc[kg][r] = -1e30f;
      }
    }
#pragma unroll
    for (int r = 0; r < 4; r++) {
      float mt = fmaxf(fmaxf(sc[0][r], sc[1][r]), fmaxf(sc[2][r], sc[3][r]));
      mt = fmaxf(mt, __shfl_xor(mt, 1, 64));
      mt = fmaxf(mt, __shfl_xor(mt, 2, 64));
      mt = fmaxf(mt, __shfl_xor(mt, 4, 64));
      mt = fmaxf(mt, __shfl_xor(mt, 8, 64));
      float mnew = fmaxf(mrow[r], mt);
      float corr = __expf(mrow[r] - mnew);
      mrow[r] = mnew;
      float s = 0.f;
#pragma unroll
      for (int kg = 0; kg < 4; kg++) {
        float p = __expf(sc[kg][r] - mnew);
        sc[kg][r] = p;
        s += p;
      }
      s += __shfl_xor(s, 1, 64);
      s += __shfl_xor(s, 2, 64);
      s += __shfl_xor(s, 4, 64);
      s += __shfl_xor(s, 8, 64);
      lrow[r] = lrow[r] * corr + s;
      // per-ROW rescale: Oa[dg] components are 4 different rows; only component r belongs to this row
#pragma unroll
      for (int dg = 0; dg < 4; dg++) Oa[dg][r] *= corr;
    }
    // P -> LDS (hi/lo). Same-wave producer/consumer rows: no barrier needed.
    {
      int rb = w * 16 + lg * 4;
#pragma unroll
      for (int kg = 0; kg < 4; kg++) {
        int col = kg * 16 + l15;
#pragma unroll
        for (int r = 0; r < 4; r++) {
          float p = sc[kg][r];
          unsigned short ph = f2bf(p);
          PsH[(rb + r) * 72 + col] = ph;
          PsL[(rb + r) * 72 + col] = f2bf(p - bf2f(ph));
        }
      }
    }
    {
      int ab = (w * 16 + l15) * 72 + lg * 8;
      bf16x8 ph0 = *(const bf16x8*)&PsH[ab];
      bf16x8 ph1 = *(const bf16x8*)&PsH[ab + 32];
      bf16x8 pl0 = *(const bf16x8*)&PsL[ab];
      bf16x8 pl1 = *(const bf16x8*)&PsL[ab + 32];
#pragma unroll
      for (int dg = 0; dg < 4; dg++) {
        int vb = (dg * 16 + l15) * 72 + lg * 8;
        bf16x8 vh0 = *(const bf16x8*)&VsH[vb];
        bf16x8 vh1 = *(const bf16x8*)&VsH[vb + 32];
        bf16x8 vl0 = *(const bf16x8*)&VsL[vb];
        bf16x8 vl1 = *(const bf16x8*)&VsL[vb + 32];
        Oa[dg] = __builtin_amdgcn_mfma_f32_16x16x32_bf16(ph0, vh0, Oa[dg], 0, 0, 0);
        Oa[dg] = __builtin_amdgcn_mfma_f32_16x16x32_bf16(ph1, vh1, Oa[dg], 0, 0, 0);
        Oa[dg] = __builtin_amdgcn_mfma_f32_16x16x32_bf16(ph0, vl0, Oa[dg], 0, 0, 0);
        Oa[dg] = __builtin_amdgcn_mfma_f32_16x16x32_bf16(ph1, vl1, Oa[dg], 0, 0, 0);
        Oa[dg] = __builtin_amdgcn_mfma_f32_16x16x32_bf16(pl0, vh0, Oa[dg], 0, 0, 0);
        Oa[dg] = __builtin_amdgcn_mfma_f32_16x16x32_bf16(pl1, vh1, Oa[dg], 0, 0, 0);
      }
    }
  }
#pragma unroll
  for (int r = 0; r < 4; r++) {
    float inv = 1.0f / lrow[r];
    size_t rowoff = (size_t)(qb + w * 16 + lg * 4 + r) * (HQ_ * D_) + head * 64;
#pragma unroll
    for (int dg = 0; dg < 4; dg++)
      attnb[rowoff + dg * 16 + l15] = Oa[dg][r] * inv;
  }
}

// ---------------- router: logits, top-2, weights, expert counts ----------------
__global__ __launch_bounds__(256) void k_router(const float* __restrict__ h2, const float* __restrict__ gw,
                                                int* __restrict__ topi, float* __restrict__ topw,
                                                int* __restrict__ counts) {
  int wid = threadIdx.x >> 6, lane = threadIdx.x & 63;
  int t = blockIdx.x * 4 + wid;
  const float* hr = h2 + (size_t)t * H_;
  float hv[16];
#pragma unroll
  for (int i = 0; i < 16; i++) hv[i] = hr[lane + 64 * i];
  float le[8];
#pragma unroll
  for (int e = 0; e < 8; e++) {
    const float* g = gw + (size_t)e * H_;
    float acc = 0.f;
#pragma unroll
    for (int i = 0; i < 16; i++) acc += hv[i] * g[lane + 64 * i];
#pragma unroll
    for (int off = 32; off; off >>= 1) acc += __shfl_xor(acc, off, 64);
    le[e] = acc;
  }
  if (lane == 0) {
    int i0 = 0;
#pragma unroll
    for (int e = 1; e < 8; e++)
      if (le[e] > le[i0]) i0 = e;
    int i1 = (i0 == 0) ? 1 : 0;
#pragma unroll
    for (int e = 0; e < 8; e++) {
      if (e == i0) continue;
      if (le[e] > le[i1]) i1 = e;
    }
    float w1r = expf(le[i1] - le[i0]);
    float denom = 1.0f + w1r;
    topi[t * 2 + 0] = i0;
    topi[t * 2 + 1] = i1;
    topw[t * 2 + 0] = 1.0f / denom;
    topw[t * 2 + 1] = w1r / denom;
    atomicAdd(&counts[i0], 1);
    atomicAdd(&counts[i1], 1);
  }
}

__global__ void k_scan(const int* __restrict__ counts, int* __restrict__ offsets) {
  if (threadIdx.x == 0 && blockIdx.x == 0) {
    int off = 0;
    for (int e = 0; e < NE_; e++) { offsets[e] = off; off += counts[e]; }
  }
}

__global__ __launch_bounds__(256) void k_build(const int* __restrict__ topi, const float* __restrict__ topw,
                                               const int* __restrict__ offsets, int* __restrict__ counts2,
                                               int* __restrict__ pairs_ts, float* __restrict__ pairs_w) {
  int t = blockIdx.x * 256 + threadIdx.x;
#pragma unroll
  for (int s = 0; s < 2; s++) {
    int e = topi[t * 2 + s];
    int slot = atomicAdd(&counts2[e], 1);
    int p = offsets[e] + slot;
    pairs_ts[p] = t * 2 + s;
    pairs_w[p] = topw[t * 2 + s];
  }
}

// ---------------- MoE up: gated = silu(A@w1^T) * (A@w3^T), bf16 MFMA ----------------
__global__ __launch_bounds__(256) void k_moe_up(const unsigned short* __restrict__ h2b, const float* __restrict__ w1,
                                                const float* __restrict__ w3, const int* __restrict__ pairs_ts,
                                                const int* __restrict__ offsets, const int* __restrict__ counts,
                                                unsigned short* __restrict__ G) {
  int e = blockIdx.z;
  int ne = counts[e];
  int row0 = blockIdx.y * 128;
  if (row0 >= ne) return;
  int col0 = blockIdx.x * 64;
  int pbase = offsets[e];
  __shared__ unsigned short As[128 * 32];
  __shared__ unsigned short B1s[64 * 32];
  __shared__ unsigned short B2s[64 * 32];
  int tid = threadIdx.x, lane = tid & 63, wid = tid >> 6;
  int wr = wid >> 1, wc = wid & 1;
  f32x4 acc1[4][2], acc2[4][2];
  f32x4 z = {0.f, 0.f, 0.f, 0.f};
#pragma unroll
  for (int a = 0; a < 4; a++)
#pragma unroll
    for (int b = 0; b < 2; b++) { acc1[a][b] = z; acc2[a][b] = z; }

  for (int kb = 0; kb < H_; kb += 32) {
    __syncthreads();
    for (int c = tid; c < 512; c += 256) {
      int row = c >> 2, k16 = c & 3;
      int grow = row0 + row;
      int tok = (grow < ne) ? (pairs_ts[pbase + grow] >> 1) : 0;
      *(uint4*)&As[row * 32 + k16 * 8] = *(const uint4*)(h2b + (size_t)tok * H_ + kb + k16 * 8);
    }
    {
      int n = tid >> 2, k16 = tid & 3;
      const float* s1 = w1 + ((size_t)e * II_ + col0 + n) * H_ + kb + k16 * 8;
      float4 a = *(const float4*)s1;
      float4 b = *(const float4*)(s1 + 4);
      u16x8 t1;
      t1[0] = f2bf(a.x); t1[1] = f2bf(a.y); t1[2] = f2bf(a.z); t1[3] = f2bf(a.w);
      t1[4] = f2bf(b.x); t1[5] = f2bf(b.y); t1[6] = f2bf(b.z); t1[7] = f2bf(b.w);
      *(u16x8*)&B1s[n * 32 + k16 * 8] = t1;
      const float* s3 = w3 + ((size_t)e * II_ + col0 + n) * H_ + kb + k16 * 8;
      float4 a3 = *(const float4*)s3;
      float4 b3 = *(const float4*)(s3 + 4);
      u16x8 t3;
      t3[0] = f2bf(a3.x); t3[1] = f2bf(a3.y); t3[2] = f2bf(a3.z); t3[3] = f2bf(a3.w);
      t3[4] = f2bf(b3.x); t3[5] = f2bf(b3.y); t3[6] = f2bf(b3.z); t3[7] = f2bf(b3.w);
      *(u16x8*)&B2s[n * 32 + k16 * 8] = t3;
    }
    __syncthreads();
    bf16x8 af[4], b1f[2], b2f[2];
#pragma unroll
    for (int fa = 0; fa < 4; fa++)
      af[fa] = *(const bf16x8*)&As[(wr * 64 + fa * 16 + (lane & 15)) * 32 + (lane >> 4) * 8];
#pragma unroll
    for (int fb = 0; fb < 2; fb++) {
      b1f[fb] = *(const bf16x8*)&B1s[(wc * 32 + fb * 16 + (lane & 15)) * 32 + (lane >> 4) * 8];
      b2f[fb] = *(const bf16x8*)&B2s[(wc * 32 + fb * 16 + (lane & 15)) * 32 + (lane >> 4) * 8];
    }
#pragma unroll
    for (int fa = 0; fa < 4; fa++)
#pragma unroll
      for (int fb = 0; fb < 2; fb++) {
        acc1[fa][fb] = __builtin_amdgcn_mfma_f32_16x16x32_bf16(af[fa], b1f[fb], acc1[fa][fb], 0, 0, 0);
        acc2[fa][fb] = __builtin_amdgcn_mfma_f32_16x16x32_bf16(af[fa], b2f[fb], acc2[fa][fb], 0, 0, 0);
      }
  }
#pragma unroll
  for (int fa = 0; fa < 4; fa++)
#pragma unroll
    for (int fb = 0; fb < 2; fb++)
#pragma unroll
      for (int r = 0; r < 4; r++) {
        int prow = row0 + wr * 64 + fa * 16 + (lane >> 4) * 4 + r;
        if (prow < ne) {
          int icol = col0 + wc * 32 + fb * 16 + (lane & 15);
          float h1 = acc1[fa][fb][r], h3 = acc2[fa][fb][r];
          float g = h1 / (1.0f + __expf(-h1)) * h3;
          G[(size_t)(pbase + prow) * II_ + icol] = f2bf(g);
        }
      }
}

// ---------------- MoE down: P[t][s] = w * (G @ w2^T), bf16 MFMA ----------------
__global__ __launch_bounds__(256) void k_moe_down(const unsigned short* __restrict__ G, const float* __restrict__ w2,
                                                  const int* __restrict__ pairs_ts, const float* __restrict__ pairs_w,
                                                  const int* __restrict__ offsets, const int* __restrict__ counts,
                                                  float* __restrict__ Pbuf) {
  int e = blockIdx.z;
  int ne = counts[e];
  int row0 = blockIdx.y * 128;
  if (row0 >= ne) return;
  int col0 = blockIdx.x * 128;
  int pbase = offsets[e];
  __shared__ unsigned short As[128 * 32];
  __shared__ unsigned short Bs[128 * 32];
  int tid = threadIdx.x, lane = tid & 63, wid = tid >> 6;
  int wr = wid >> 1, wc = wid & 1;
  f32x4 acc[4][4];
  f32x4 z = {0.f, 0.f, 0.f, 0.f};
#pragma unroll
  for (int a = 0; a < 4; a++)
#pragma unroll
    for (int b = 0; b < 4; b++) acc[a][b] = z;

  for (int kb = 0; kb < II_; kb += 32) {
    __syncthreads();
    for (int c = tid; c < 512; c += 256) {
      int row = c >> 2, k16 = c & 3;
      int grow = row0 + row;
      size_t p = (size_t)pbase + ((grow < ne) ? grow : 0);
      *(uint4*)&As[row * 32 + k16 * 8] = *(const uint4*)(G + p * II_ + kb + k16 * 8);
    }
    for (int c = tid; c < 512; c += 256) {
      int n = c >> 2, k16 = c & 3;
      const float* s = w2 + ((size_t)e * H_ + col0 + n) * II_ + kb + k16 * 8;
      float4 a = *(const float4*)s;
      float4 b = *(const float4*)(s + 4);
      u16x8 tv;
      tv[0] = f2bf(a.x); tv[1] = f2bf(a.y); tv[2] = f2bf(a.z); tv[3] = f2bf(a.w);
      tv[4] = f2bf(b.x); tv[5] = f2bf(b.y); tv[6] = f2bf(b.z); tv[7] = f2bf(b.w);
      *(u16x8*)&Bs[n * 32 + k16 * 8] = tv;
    }
    __syncthreads();
    bf16x8 af[4], bf[4];
#pragma unroll
    for (int fa = 0; fa < 4; fa++)
      af[fa] = *(const bf16x8*)&As[(wr * 64 + fa * 16 + (lane & 15)) * 32 + (lane >> 4) * 8];
#pragma unroll
    for (int fb = 0; fb < 4; fb++)
      bf[fb] = *(const bf16x8*)&Bs[(wc * 64 + fb * 16 + (lane & 15)) * 32 + (lane >> 4) * 8];
#pragma unroll
    for (int fa = 0; fa < 4; fa++)
#pragma unroll
      for (int fb = 0; fb < 4; fb++)
        acc[fa][fb] = __builtin_amdgcn_mfma_f32_16x16x32_bf16(af[fa], bf[fb], acc[fa][fb], 0, 0, 0);
  }
#pragma unroll
  for (int fa = 0; fa < 4; fa++)
#pragma unroll
    for (int fb = 0; fb < 4; fb++)
#pragma unroll
      for (int r = 0; r < 4; r++) {
        int prow = row0 + wr * 64 + fa * 16 + (lane >> 4) * 4 + r;
        if (prow < ne) {
          int p = pbase + prow;
          int ts = pairs_ts[p];
          float wgt = pairs_w[p];
          int col = col0 + wc * 64 + fb * 16 + (lane & 15);
          Pbuf[(size_t)ts * H_ + col] = wgt * acc[fa][fb][r];
        }
      }
}

// ---------------- final: out = rmsnorm(resid + P0 + P1) ----------------
__global__ __launch_bounds__(256) void k_final(const float* __restrict__ resid, const float* __restrict__ Pbuf,
                                               const float* __restrict__ w, float* __restrict__ out) {
  int row = blockIdx.x;
  int tid = threadIdx.x;
  float4 a = ((const float4*)(resid + (size_t)row * H_))[tid];
  float4 p0 = ((const float4*)(Pbuf + (size_t)(2 * row) * H_))[tid];
  float4 p1 = ((const float4*)(Pbuf + (size_t)(2 * row + 1) * H_))[tid];
  float4 v;
  v.x = a.x + p0.x + p1.x; v.y = a.y + p0.y + p1.y; v.z = a.z + p0.z + p1.z; v.w = a.w + p0.w + p1.w;
  float ss = v.x * v.x + v.y * v.y + v.z * v.z + v.w * v.w;
#pragma unroll
  for (int off = 32; off; off >>= 1) ss += __shfl_xor(ss, off, 64);
  __shared__ float red[4];
  int lane = tid & 63, wid = tid >> 6;
  if (lane == 0) red[wid] = ss;
  __syncthreads();
  float tot = red[0] + red[1] + red[2] + red[3];
  float inv = rsqrtf(tot * (1.0f / H_) + 1e-5f);
  float4 wv = ((const float4*)w)[tid];
  float4 o;
  o.x = v.x * inv * wv.x; o.y = v.y * inv * wv.y; o.z = v.z * inv * wv.z; o.w = v.w * inv * wv.w;
  ((float4*)(out + (size_t)row * H_))[tid] = o;
}

extern "C" void kernel_launch(void* const* d_in, const int* in_sizes, int n_in,
                              void* d_out, int out_size, void* d_ws, size_t ws_size,
                              hipStream_t stream) {
  const float* x = (const float*)d_in[0];
  const int* pos = (const int*)d_in[1];
  const float* qkv_w = (const float*)d_in[2];
  const float* o_w = (const float*)d_in[3];
  const float* nin_w = (const float*)d_in[4];
  const float* npost_w = (const float*)d_in[5];
  const float* nnext_w = (const float*)d_in[6];
  const float* gate_w = (const float*)d_in[7];
  const float* w1 = (const float*)d_in[8];
  const float* w3 = (const float*)d_in[9];
  const float* w2 = (const float*)d_in[10];
  float* out = (float*)d_out;

  float* f = (float*)d_ws;
  float* h_in = f;   f += (size_t)T_ * H_;          // dead after qkv gemm -> Pbuf alias
  float* qkvb = f;   f += (size_t)T_ * 1536;        // dead after rope/vtrans -> Pbuf alias
  float* attnb = f;  f += (size_t)T_ * HQ_ * D_;
  float* resid = f;  f += (size_t)T_ * H_;
  float* h2 = f;     f += (size_t)T_ * H_;
  float* ct = f;     f += (size_t)T_ * 32;
  float* st = f;     f += (size_t)T_ * 32;
  float* topw = f;   f += (size_t)T_ * 2;
  float* pairsw = f; f += 4096;
  float* Pbuf = h_in;  // alias (needs 4M floats; h_in+qkvb = 5M floats, both dead by MoE)
  unsigned short* u = (unsigned short*)f;
  unsigned short* h2b = u;  u += (size_t)T_ * H_;
  unsigned short* G = u;    u += (size_t)2 * T_ * II_;
  unsigned short* Qhi = u;  u += (size_t)HQ_ * T_ * D_;
  unsigned short* Qlo = u;  u += (size_t)HQ_ * T_ * D_;
  unsigned short* Khi = u;  u += (size_t)HK_ * T_ * D_;
  unsigned short* Klo = u;  u += (size_t)HK_ * T_ * D_;
  unsigned short* Vthi = u; u += (size_t)HK_ * D_ * T_;
  unsigned short* Vtlo = u; u += (size_t)HK_ * D_ * T_;
  int* topi = (int*)u;
  int* ctrl = topi + T_ * 2;
  int* counts = ctrl;
  int* counts2 = ctrl + 8;
  int* offsets = ctrl + 16;
  int* pairs_ts = ctrl + 24;

  hipMemsetAsync(ctrl, 0, 64, stream);  // counts + counts2
  k_rmsnorm<<<T_, 256, 0, stream>>>(x, nin_w, h_in, (unsigned short*)nullptr);
  k_sgemm_nt<0><<<dim3((HQ_ + 2 * HK_) * D_ / 64, T_ / 64), 256, 0, stream>>>(h_in, qkv_w, qkvb, nullptr, T_,
                                                                              (HQ_ + 2 * HK_) * D_, H_);
  k_rope_table<<<T_ * 32 / 256, 256, 0, stream>>>(pos, ct, st);
  k_rope_prep<<<T_, 256, 0, stream>>>(qkvb, ct, st, Qhi, Qlo, Khi, Klo);
  k_vtrans<<<dim3(T_ / 64, HK_), 256, 0, stream>>>(qkvb, Vthi, Vtlo);
  k_attn_mfma<<<dim3(512), 256, 0, stream>>>(Qhi, Qlo, Khi, Klo, Vthi, Vtlo, attnb);
  k_sgemm_nt<1><<<dim3(H_ / 64, T_ / 64), 256, 0, stream>>>(attnb, o_w, resid, x, T_, H_, HQ_ * D_);
  k_rmsnorm<<<T_, 256, 0, stream>>>(resid, npost_w, h2, h2b);
  k_router<<<T_ / 4, 256, 0, stream>>>(h2, gate_w, topi, topw, counts);
  k_scan<<<1, 64, 0, stream>>>(counts, offsets);
  k_build<<<T_ / 256, 256, 0, stream>>>(topi, topw, offsets, counts2, pairs_ts, pairsw);
  k_moe_up<<<dim3(II_ / 64, T_ / 128, NE_), 256, 0, stream>>>(h2b, w1, w3, pairs_ts, offsets, counts, G);
  k_moe_down<<<dim3(H_ / 128, T_ / 128, NE_), 256, 0, stream>>>(G, w2, pairs_ts, pairsw, offsets, counts, Pbuf);
  k_final<<<T_, 256, 0, stream>>>(resid, Pbuf, nnext_w, out);
}

// Round 4
// 592.449 us; speedup vs baseline: 1.5202x; 1.1926x over previous
//
#include <hip/hip_runtime.h>
#include <hip/hip_bf16.h>
#include <math.h>

#define T_ 2048
#define H_ 1024
#define HQ_ 16
#define HK_ 4
#define D_ 64
#define NE_ 8
#define II_ 2048

typedef __attribute__((ext_vector_type(8))) short bf16x8;
typedef __attribute__((ext_vector_type(8))) unsigned short u16x8;
typedef __attribute__((ext_vector_type(4))) float f32x4;

__device__ __forceinline__ unsigned short f2bf(float f) {
  unsigned int u = __float_as_uint(f);
  return (unsigned short)((u + 0x7fffu + ((u >> 16) & 1u)) >> 16);
}
__device__ __forceinline__ float bf2f(unsigned short h) {
  return __uint_as_float((unsigned int)h << 16);
}

// ---------------- rmsnorm (fp32 in, fp32 out + optional bf16 out) ----------------
__global__ __launch_bounds__(256) void k_rmsnorm(const float* __restrict__ x, const float* __restrict__ w,
                                                 float* __restrict__ outf, unsigned short* __restrict__ outb) {
  int row = blockIdx.x;
  int tid = threadIdx.x;
  float4 v = ((const float4*)(x + (size_t)row * H_))[tid];
  float ss = v.x * v.x + v.y * v.y + v.z * v.z + v.w * v.w;
#pragma unroll
  for (int off = 32; off; off >>= 1) ss += __shfl_xor(ss, off, 64);
  __shared__ float red[4];
  int lane = tid & 63, wid = tid >> 6;
  if (lane == 0) red[wid] = ss;
  __syncthreads();
  float tot = red[0] + red[1] + red[2] + red[3];
  float inv = rsqrtf(tot * (1.0f / H_) + 1e-5f);
  float4 wv = ((const float4*)w)[tid];
  float4 o;
  o.x = v.x * inv * wv.x; o.y = v.y * inv * wv.y; o.z = v.z * inv * wv.z; o.w = v.w * inv * wv.w;
  ((float4*)(outf + (size_t)row * H_))[tid] = o;
  if (outb) {
    ushort4 b; b.x = f2bf(o.x); b.y = f2bf(o.y); b.z = f2bf(o.z); b.w = f2bf(o.w);
    ((ushort4*)(outb + (size_t)row * H_))[tid] = b;
  }
}

// ---------------- fp32 GEMM: C[M][N] = A[M][K] @ B[N][K]^T (+ optional add) ----------------
template <int ADD>
__global__ __launch_bounds__(256) void k_sgemm_nt(const float* __restrict__ A, const float* __restrict__ B,
                                                  float* __restrict__ C, const float* __restrict__ addsrc,
                                                  int M, int N, int K) {
  __shared__ float As[32 * 68];
  __shared__ float Bs[32 * 68];
  int m0 = blockIdx.y * 64, n0 = blockIdx.x * 64;
  int tid = threadIdx.x, tx = tid & 15, ty = tid >> 4;
  float acc[4][4];
#pragma unroll
  for (int i = 0; i < 4; i++)
#pragma unroll
    for (int j = 0; j < 4; j++) acc[i][j] = 0.f;

  for (int kb = 0; kb < K; kb += 32) {
    __syncthreads();
    for (int c = tid; c < 512; c += 256) {
      int row = c >> 3, kc = c & 7;
      float4 va = *(const float4*)(A + (size_t)(m0 + row) * K + kb + kc * 4);
      As[(kc * 4 + 0) * 68 + row] = va.x;
      As[(kc * 4 + 1) * 68 + row] = va.y;
      As[(kc * 4 + 2) * 68 + row] = va.z;
      As[(kc * 4 + 3) * 68 + row] = va.w;
      float4 vb = *(const float4*)(B + (size_t)(n0 + row) * K + kb + kc * 4);
      Bs[(kc * 4 + 0) * 68 + row] = vb.x;
      Bs[(kc * 4 + 1) * 68 + row] = vb.y;
      Bs[(kc * 4 + 2) * 68 + row] = vb.z;
      Bs[(kc * 4 + 3) * 68 + row] = vb.w;
    }
    __syncthreads();
#pragma unroll 16
    for (int kk = 0; kk < 32; ++kk) {
      float4 av = *(const float4*)&As[kk * 68 + ty * 4];
      float4 bv = *(const float4*)&Bs[kk * 68 + tx * 4];
      acc[0][0] += av.x * bv.x; acc[0][1] += av.x * bv.y; acc[0][2] += av.x * bv.z; acc[0][3] += av.x * bv.w;
      acc[1][0] += av.y * bv.x; acc[1][1] += av.y * bv.y; acc[1][2] += av.y * bv.z; acc[1][3] += av.y * bv.w;
      acc[2][0] += av.z * bv.x; acc[2][1] += av.z * bv.y; acc[2][2] += av.z * bv.z; acc[2][3] += av.z * bv.w;
      acc[3][0] += av.w * bv.x; acc[3][1] += av.w * bv.y; acc[3][2] += av.w * bv.z; acc[3][3] += av.w * bv.w;
    }
  }
#pragma unroll
  for (int i = 0; i < 4; i++) {
    size_t off = (size_t)(m0 + ty * 4 + i) * N + n0 + tx * 4;
    float4 o; o.x = acc[i][0]; o.y = acc[i][1]; o.z = acc[i][2]; o.w = acc[i][3];
    if (ADD) {
      float4 ad = *(const float4*)(addsrc + off);
      o.x += ad.x; o.y += ad.y; o.z += ad.z; o.w += ad.w;
    }
    *(float4*)(C + off) = o;
  }
}

// ---------------- RoPE cos/sin table (matches np float32 angle bits) ----------------
__global__ __launch_bounds__(256) void k_rope_table(const int* __restrict__ pos, float* __restrict__ ct,
                                                    float* __restrict__ st) {
  int idx = blockIdx.x * 256 + threadIdx.x;  // T*32
  int t = idx >> 5, i = idx & 31;
  float p = (float)pow(10000.0, (double)i / 32.0);
  float freq = 1.0f / p;
  float ang = (float)pos[t] * freq;
  ct[idx] = cosf(ang);
  st[idx] = sinf(ang);
}

// ---------------- RoPE apply + bf16 hi/lo split ----------------
__global__ __launch_bounds__(256) void k_rope_prep(const float* __restrict__ qkv, const float* __restrict__ ct,
                                                   const float* __restrict__ st, unsigned short* __restrict__ Qhi,
                                                   unsigned short* __restrict__ Qlo, unsigned short* __restrict__ Khi,
                                                   unsigned short* __restrict__ Klo) {
  int t = blockIdx.x, tid = threadIdx.x;
  const float* row = qkv + (size_t)t * 1536;
#pragma unroll 2
  for (int it = tid; it < 512; it += 256) {
    int h = it >> 5, i = it & 31;
    float c = ct[t * 32 + i], s = st[t * 32 + i];
    float x1 = row[h * 64 + i], x2 = row[h * 64 + i + 32];
    float a = (x1 * c - x2 * s) * 0.125f;
    float b = (x2 * c + x1 * s) * 0.125f;
    size_t base = ((size_t)h * T_ + t) * 64 + i;
    unsigned short ah = f2bf(a), bh = f2bf(b);
    Qhi[base] = ah; Qhi[base + 32] = bh;
    Qlo[base] = f2bf(a - bf2f(ah));
    Qlo[base + 32] = f2bf(b - bf2f(bh));
  }
  if (tid < 128) {
    int h = tid >> 5, i = tid & 31;
    float c = ct[t * 32 + i], s = st[t * 32 + i];
    float x1 = row[1024 + h * 64 + i], x2 = row[1024 + h * 64 + i + 32];
    float a = x1 * c - x2 * s;
    float b = x2 * c + x1 * s;
    size_t base = ((size_t)h * T_ + t) * 64 + i;
    unsigned short ah = f2bf(a), bh = f2bf(b);
    Khi[base] = ah; Khi[base + 32] = bh;
    Klo[base] = f2bf(a - bf2f(ah));
    Klo[base + 32] = f2bf(b - bf2f(bh));
  }
}

// ---------------- V transpose + split: Vthi/Vtlo [kvh][d][t] ----------------
__global__ __launch_bounds__(256) void k_vtrans(const float* __restrict__ qkv, unsigned short* __restrict__ Vthi,
                                                unsigned short* __restrict__ Vtlo) {
  int t0 = blockIdx.x * 64, h = blockIdx.y;
  __shared__ float tile[64][65];
  int tid = threadIdx.x;
  int c = tid & 63, w = tid >> 6;
  for (int r = w; r < 64; r += 4)
    tile[r][c] = qkv[(size_t)(t0 + r) * 1536 + 1280 + h * 64 + c];
  __syncthreads();
  for (int d = w; d < 64; d += 4) {
    float v = tile[c][d];
    unsigned short hi = f2bf(v);
    size_t idx = ((size_t)h * 64 + d) * T_ + t0 + c;
    Vthi[idx] = hi;
    Vtlo[idx] = f2bf(v - bf2f(hi));
  }
}

// ---------------- flash attention, bf16x3 split MFMA (fp32-grade precision) ----------------
__global__ __launch_bounds__(256) void k_attn_mfma(const unsigned short* __restrict__ Qhi,
                                                   const unsigned short* __restrict__ Qlo,
                                                   const unsigned short* __restrict__ Khi,
                                                   const unsigned short* __restrict__ Klo,
                                                   const unsigned short* __restrict__ Vthi,
                                                   const unsigned short* __restrict__ Vtlo,
                                                   float* __restrict__ attnb) {
  int bid = blockIdx.x;
  int kk = bid >> 4;
  int head = bid & 15;
  int qidx = (kk < 16) ? (31 - kk) : (kk - 16);
  int qb = qidx * 64;
  int kvh = head >> 2;
  int tid = threadIdx.x, lane = tid & 63, w = tid >> 6;
  int l15 = lane & 15, lg = lane >> 4;

  __shared__ unsigned short KsH[64 * 72], KsL[64 * 72];
  __shared__ unsigned short VsH[64 * 72], VsL[64 * 72];
  __shared__ unsigned short PsH[64 * 72], PsL[64 * 72];

  bf16x8 qh[2], ql[2];
  {
    size_t qbase = ((size_t)head * T_ + qb + w * 16 + l15) * 64 + lg * 8;
    qh[0] = *(const bf16x8*)(Qhi + qbase);
    qh[1] = *(const bf16x8*)(Qhi + qbase + 32);
    ql[0] = *(const bf16x8*)(Qlo + qbase);
    ql[1] = *(const bf16x8*)(Qlo + qbase + 32);
  }
  f32x4 z = {0.f, 0.f, 0.f, 0.f};
  f32x4 Oa[4];
  float mrow[4], lrow[4];
#pragma unroll
  for (int r = 0; r < 4; r++) { mrow[r] = -1e30f; lrow[r] = 0.f; }
#pragma unroll
  for (int dg = 0; dg < 4; dg++) Oa[dg] = z;

  for (int jb = 0; jb <= qb; jb += 64) {
    __syncthreads();
    for (int c = tid; c < 512; c += 256) {
      int r = c >> 3, g = (c & 7) * 8;
      size_t kgl = ((size_t)kvh * T_ + jb + r) * 64 + g;
      size_t vgl = ((size_t)kvh * 64 + r) * T_ + jb + g;
      *(uint4*)&KsH[r * 72 + g] = *(const uint4*)(Khi + kgl);
      *(uint4*)&KsL[r * 72 + g] = *(const uint4*)(Klo + kgl);
      *(uint4*)&VsH[r * 72 + g] = *(const uint4*)(Vthi + vgl);
      *(uint4*)&VsL[r * 72 + g] = *(const uint4*)(Vtlo + vgl);
    }
    __syncthreads();

    f32x4 sc[4];
    sc[0] = z; sc[1] = z; sc[2] = z; sc[3] = z;
#pragma unroll
    for (int kg = 0; kg < 4; kg++) {
      int ba = (kg * 16 + l15) * 72 + lg * 8;
      bf16x8 bh0 = *(const bf16x8*)&KsH[ba];
      bf16x8 bh1 = *(const bf16x8*)&KsH[ba + 32];
      bf16x8 bl0 = *(const bf16x8*)&KsL[ba];
      bf16x8 bl1 = *(const bf16x8*)&KsL[ba + 32];
      sc[kg] = __builtin_amdgcn_mfma_f32_16x16x32_bf16(qh[0], bh0, sc[kg], 0, 0, 0);
      sc[kg] = __builtin_amdgcn_mfma_f32_16x16x32_bf16(qh[1], bh1, sc[kg], 0, 0, 0);
      sc[kg] = __builtin_amdgcn_mfma_f32_16x16x32_bf16(qh[0], bl0, sc[kg], 0, 0, 0);
      sc[kg] = __builtin_amdgcn_mfma_f32_16x16x32_bf16(qh[1], bl1, sc[kg], 0, 0, 0);
      sc[kg] = __builtin_amdgcn_mfma_f32_16x16x32_bf16(ql[0], bh0, sc[kg], 0, 0, 0);
      sc[kg] = __builtin_amdgcn_mfma_f32_16x16x32_bf16(ql[1], bh1, sc[kg], 0, 0, 0);
    }
    if (jb == qb) {
      int rb = w * 16 + lg * 4;
#pragma unroll
      for (int kg = 0; kg < 4; kg++) {
        int col = kg * 16 + l15;
#pragma unroll
        for (int r = 0; r < 4; r++)
          if (col > rb + r) sc[kg][r] = -1e30f;
      }
    }
#pragma unroll
    for (int r = 0; r < 4; r++) {
      float mt = fmaxf(fmaxf(sc[0][r], sc[1][r]), fmaxf(sc[2][r], sc[3][r]));
      mt = fmaxf(mt, __shfl_xor(mt, 1, 64));
      mt = fmaxf(mt, __shfl_xor(mt, 2, 64));
      mt = fmaxf(mt, __shfl_xor(mt, 4, 64));
      mt = fmaxf(mt, __shfl_xor(mt, 8, 64));
      float mnew = fmaxf(mrow[r], mt);
      float corr = __expf(mrow[r] - mnew);
      mrow[r] = mnew;
      float s = 0.f;
#pragma unroll
      for (int kg = 0; kg < 4; kg++) {
        float p = __expf(sc[kg][r] - mnew);
        sc[kg][r] = p;
        s += p;
      }
      s += __shfl_xor(s, 1, 64);
      s += __shfl_xor(s, 2, 64);
      s += __shfl_xor(s, 4, 64);
      s += __shfl_xor(s, 8, 64);
      lrow[r] = lrow[r] * corr + s;
      // per-ROW rescale (Oa[dg] components are 4 different rows)
#pragma unroll
      for (int dg = 0; dg < 4; dg++) Oa[dg][r] *= corr;
    }
    {
      int rb = w * 16 + lg * 4;
#pragma unroll
      for (int kg = 0; kg < 4; kg++) {
        int col = kg * 16 + l15;
#pragma unroll
        for (int r = 0; r < 4; r++) {
          float p = sc[kg][r];
          unsigned short ph = f2bf(p);
          PsH[(rb + r) * 72 + col] = ph;
          PsL[(rb + r) * 72 + col] = f2bf(p - bf2f(ph));
        }
      }
    }
    {
      int ab = (w * 16 + l15) * 72 + lg * 8;
      bf16x8 ph0 = *(const bf16x8*)&PsH[ab];
      bf16x8 ph1 = *(const bf16x8*)&PsH[ab + 32];
      bf16x8 pl0 = *(const bf16x8*)&PsL[ab];
      bf16x8 pl1 = *(const bf16x8*)&PsL[ab + 32];
#pragma unroll
      for (int dg = 0; dg < 4; dg++) {
        int vb = (dg * 16 + l15) * 72 + lg * 8;
        bf16x8 vh0 = *(const bf16x8*)&VsH[vb];
        bf16x8 vh1 = *(const bf16x8*)&VsH[vb + 32];
        bf16x8 vl0 = *(const bf16x8*)&VsL[vb];
        bf16x8 vl1 = *(const bf16x8*)&VsL[vb + 32];
        Oa[dg] = __builtin_amdgcn_mfma_f32_16x16x32_bf16(ph0, vh0, Oa[dg], 0, 0, 0);
        Oa[dg] = __builtin_amdgcn_mfma_f32_16x16x32_bf16(ph1, vh1, Oa[dg], 0, 0, 0);
        Oa[dg] = __builtin_amdgcn_mfma_f32_16x16x32_bf16(ph0, vl0, Oa[dg], 0, 0, 0);
        Oa[dg] = __builtin_amdgcn_mfma_f32_16x16x32_bf16(ph1, vl1, Oa[dg], 0, 0, 0);
        Oa[dg] = __builtin_amdgcn_mfma_f32_16x16x32_bf16(pl0, vh0, Oa[dg], 0, 0, 0);
        Oa[dg] = __builtin_amdgcn_mfma_f32_16x16x32_bf16(pl1, vh1, Oa[dg], 0, 0, 0);
      }
    }
  }
#pragma unroll
  for (int r = 0; r < 4; r++) {
    float inv = 1.0f / lrow[r];
    size_t rowoff = (size_t)(qb + w * 16 + lg * 4 + r) * (HQ_ * D_) + head * 64;
#pragma unroll
    for (int dg = 0; dg < 4; dg++)
      attnb[rowoff + dg * 16 + l15] = Oa[dg][r] * inv;
  }
}

// ---------------- router ----------------
__global__ __launch_bounds__(256) void k_router(const float* __restrict__ h2, const float* __restrict__ gw,
                                                int* __restrict__ topi, float* __restrict__ topw,
                                                int* __restrict__ counts) {
  int wid = threadIdx.x >> 6, lane = threadIdx.x & 63;
  int t = blockIdx.x * 4 + wid;
  const float* hr = h2 + (size_t)t * H_;
  float hv[16];
#pragma unroll
  for (int i = 0; i < 16; i++) hv[i] = hr[lane + 64 * i];
  float le[8];
#pragma unroll
  for (int e = 0; e < 8; e++) {
    const float* g = gw + (size_t)e * H_;
    float acc = 0.f;
#pragma unroll
    for (int i = 0; i < 16; i++) acc += hv[i] * g[lane + 64 * i];
#pragma unroll
    for (int off = 32; off; off >>= 1) acc += __shfl_xor(acc, off, 64);
    le[e] = acc;
  }
  if (lane == 0) {
    int i0 = 0;
#pragma unroll
    for (int e = 1; e < 8; e++)
      if (le[e] > le[i0]) i0 = e;
    int i1 = (i0 == 0) ? 1 : 0;
#pragma unroll
    for (int e = 0; e < 8; e++) {
      if (e == i0) continue;
      if (le[e] > le[i1]) i1 = e;
    }
    float w1r = expf(le[i1] - le[i0]);
    float denom = 1.0f + w1r;
    topi[t * 2 + 0] = i0;
    topi[t * 2 + 1] = i1;
    topw[t * 2 + 0] = 1.0f / denom;
    topw[t * 2 + 1] = w1r / denom;
    atomicAdd(&counts[i0], 1);
    atomicAdd(&counts[i1], 1);
  }
}

__global__ void k_scan(const int* __restrict__ counts, int* __restrict__ offsets) {
  if (threadIdx.x == 0 && blockIdx.x == 0) {
    int off = 0;
    for (int e = 0; e < NE_; e++) { offsets[e] = off; off += counts[e]; }
  }
}

__global__ __launch_bounds__(256) void k_build(const int* __restrict__ topi, const float* __restrict__ topw,
                                               const int* __restrict__ offsets, int* __restrict__ counts2,
                                               int* __restrict__ pairs_ts, float* __restrict__ pairs_w) {
  int t = blockIdx.x * 256 + threadIdx.x;
#pragma unroll
  for (int s = 0; s < 2; s++) {
    int e = topi[t * 2 + s];
    int slot = atomicAdd(&counts2[e], 1);
    int p = offsets[e] + slot;
    pairs_ts[p] = t * 2 + s;
    pairs_w[p] = topw[t * 2 + s];
  }
}

// ---------------- fp32 -> bf16 bulk convert (8 elems/thread/iter, grid-stride) ----------------
__global__ __launch_bounds__(256) void k_conv(const float* __restrict__ in, unsigned short* __restrict__ out, int n8) {
  int stride = gridDim.x * 256;
  for (int i = blockIdx.x * 256 + threadIdx.x; i < n8; i += stride) {
    const float4* p = (const float4*)in + (size_t)i * 2;
    float4 a = p[0], b = p[1];
    u16x8 t;
    t[0] = f2bf(a.x); t[1] = f2bf(a.y); t[2] = f2bf(a.z); t[3] = f2bf(a.w);
    t[4] = f2bf(b.x); t[5] = f2bf(b.y); t[6] = f2bf(b.z); t[7] = f2bf(b.w);
    *((u16x8*)out + i) = t;
  }
}

// ---------------- MoE up: 128x64 tile, BK=64, dbuf LDS (1 barrier/step), bf16 weights ----------------
__global__ __launch_bounds__(256) void k_moe_up(const unsigned short* __restrict__ h2b, const unsigned short* __restrict__ W1b,
                                                const unsigned short* __restrict__ W3b, const int* __restrict__ pairs_ts,
                                                const int* __restrict__ offsets, const int* __restrict__ counts,
                                                unsigned short* __restrict__ G) {
  int e = blockIdx.z;
  int ne = counts[e];
  int row0 = blockIdx.y * 128;
  if (row0 >= ne) return;
  int col0 = blockIdx.x * 64;
  int pbase = offsets[e];
  __shared__ unsigned short As[2][128 * 72];
  __shared__ unsigned short B1s[2][64 * 72];
  __shared__ unsigned short B2s[2][64 * 72];
  int tid = threadIdx.x, lane = tid & 63, wid = tid >> 6;
  int wr = wid >> 1, wc = wid & 1;
  int l15 = lane & 15, lg = lane >> 4;
  int arow = tid >> 3, akg = (tid & 7) * 8;

  // hoisted gather offsets: A rows arow+32i -> token rows of h2b
  int aoff[4];
#pragma unroll
  for (int i = 0; i < 4; i++) {
    int grow = row0 + arow + 32 * i;
    int tok = (grow < ne) ? (pairs_ts[pbase + grow] >> 1) : 0;
    aoff[i] = tok * H_ + akg;
  }
  size_t bbase = ((size_t)e * II_ + col0 + arow) * H_ + akg;  // rows arow, arow+32

  f32x4 acc1[4][2], acc2[4][2];
  f32x4 z = {0.f, 0.f, 0.f, 0.f};
#pragma unroll
  for (int a = 0; a < 4; a++)
#pragma unroll
    for (int b = 0; b < 2; b++) { acc1[a][b] = z; acc2[a][b] = z; }

  uint4 pa[4], pb1[2], pb2[2];
#pragma unroll
  for (int i = 0; i < 4; i++) pa[i] = *(const uint4*)(h2b + aoff[i]);
#pragma unroll
  for (int j = 0; j < 2; j++) {
    pb1[j] = *(const uint4*)(W1b + bbase + (size_t)j * 32 * H_);
    pb2[j] = *(const uint4*)(W3b + bbase + (size_t)j * 32 * H_);
  }
#pragma unroll
  for (int i = 0; i < 4; i++) *(uint4*)&As[0][(arow + 32 * i) * 72 + akg] = pa[i];
#pragma unroll
  for (int j = 0; j < 2; j++) {
    *(uint4*)&B1s[0][(arow + 32 * j) * 72 + akg] = pb1[j];
    *(uint4*)&B2s[0][(arow + 32 * j) * 72 + akg] = pb2[j];
  }
  __syncthreads();
  int cur = 0;
  for (int t = 0; t < H_ / 64; ++t) {
    if (t < H_ / 64 - 1) {
      int kn = (t + 1) * 64;
#pragma unroll
      for (int i = 0; i < 4; i++) pa[i] = *(const uint4*)(h2b + aoff[i] + kn);
#pragma unroll
      for (int j = 0; j < 2; j++) {
        pb1[j] = *(const uint4*)(W1b + bbase + (size_t)j * 32 * H_ + kn);
        pb2[j] = *(const uint4*)(W3b + bbase + (size_t)j * 32 * H_ + kn);
      }
    }
#pragma unroll
    for (int kk = 0; kk < 2; kk++) {
      bf16x8 af[4], b1f[2], b2f[2];
#pragma unroll
      for (int fa = 0; fa < 4; fa++)
        af[fa] = *(const bf16x8*)&As[cur][(wr * 64 + fa * 16 + l15) * 72 + kk * 32 + lg * 8];
#pragma unroll
      for (int fb = 0; fb < 2; fb++) {
        b1f[fb] = *(const bf16x8*)&B1s[cur][(wc * 32 + fb * 16 + l15) * 72 + kk * 32 + lg * 8];
        b2f[fb] = *(const bf16x8*)&B2s[cur][(wc * 32 + fb * 16 + l15) * 72 + kk * 32 + lg * 8];
      }
#pragma unroll
      for (int fa = 0; fa < 4; fa++)
#pragma unroll
        for (int fb = 0; fb < 2; fb++) {
          acc1[fa][fb] = __builtin_amdgcn_mfma_f32_16x16x32_bf16(af[fa], b1f[fb], acc1[fa][fb], 0, 0, 0);
          acc2[fa][fb] = __builtin_amdgcn_mfma_f32_16x16x32_bf16(af[fa], b2f[fb], acc2[fa][fb], 0, 0, 0);
        }
    }
    if (t < H_ / 64 - 1) {
#pragma unroll
      for (int i = 0; i < 4; i++) *(uint4*)&As[cur ^ 1][(arow + 32 * i) * 72 + akg] = pa[i];
#pragma unroll
      for (int j = 0; j < 2; j++) {
        *(uint4*)&B1s[cur ^ 1][(arow + 32 * j) * 72 + akg] = pb1[j];
        *(uint4*)&B2s[cur ^ 1][(arow + 32 * j) * 72 + akg] = pb2[j];
      }
    }
    __syncthreads();
    cur ^= 1;
  }
#pragma unroll
  for (int fa = 0; fa < 4; fa++)
#pragma unroll
    for (int r = 0; r < 4; r++) {
      int prow = row0 + wr * 64 + fa * 16 + lg * 4 + r;
      if (prow < ne) {
#pragma unroll
        for (int fb = 0; fb < 2; fb++) {
          int icol = col0 + wc * 32 + fb * 16 + l15;
          float h1 = acc1[fa][fb][r], h3 = acc2[fa][fb][r];
          float g = h1 / (1.0f + __expf(-h1)) * h3;
          G[(size_t)(pbase + prow) * II_ + icol] = f2bf(g);
        }
      }
    }
}

// ---------------- MoE down: 128x64 tile, BK=64, dbuf LDS (1 barrier/step), bf16 W2 ----------------
__global__ __launch_bounds__(256) void k_moe_down(const unsigned short* __restrict__ G, const unsigned short* __restrict__ W2b,
                                                  const int* __restrict__ pairs_ts, const float* __restrict__ pairs_w,
                                                  const int* __restrict__ offsets, const int* __restrict__ counts,
                                                  float* __restrict__ Pbuf) {
  int e = blockIdx.z;
  int ne = counts[e];
  int row0 = blockIdx.y * 128;
  if (row0 >= ne) return;
  int col0 = blockIdx.x * 64;
  int pbase = offsets[e];
  __shared__ unsigned short As[2][128 * 72];
  __shared__ unsigned short Bs[2][64 * 72];
  int tid = threadIdx.x, lane = tid & 63, wid = tid >> 6;
  int wr = wid >> 1, wc = wid & 1;
  int l15 = lane & 15, lg = lane >> 4;
  int arow = tid >> 3, akg = (tid & 7) * 8;

  int aoff[4];
#pragma unroll
  for (int i = 0; i < 4; i++) {
    int grow = row0 + arow + 32 * i;
    int p = pbase + ((grow < ne) ? grow : 0);
    aoff[i] = p * II_ + akg;
  }
  size_t bbase = ((size_t)e * H_ + col0 + arow) * II_ + akg;

  f32x4 acc[4][2];
  f32x4 z = {0.f, 0.f, 0.f, 0.f};
#pragma unroll
  for (int a = 0; a < 4; a++)
#pragma unroll
    for (int b = 0; b < 2; b++) acc[a][b] = z;

  uint4 pa[4], pb[2];
#pragma unroll
  for (int i = 0; i < 4; i++) pa[i] = *(const uint4*)(G + aoff[i]);
#pragma unroll
  for (int j = 0; j < 2; j++) pb[j] = *(const uint4*)(W2b + bbase + (size_t)j * 32 * II_);
#pragma unroll
  for (int i = 0; i < 4; i++) *(uint4*)&As[0][(arow + 32 * i) * 72 + akg] = pa[i];
#pragma unroll
  for (int j = 0; j < 2; j++) *(uint4*)&Bs[0][(arow + 32 * j) * 72 + akg] = pb[j];
  __syncthreads();
  int cur = 0;
  for (int t = 0; t < II_ / 64; ++t) {
    if (t < II_ / 64 - 1) {
      int kn = (t + 1) * 64;
#pragma unroll
      for (int i = 0; i < 4; i++) pa[i] = *(const uint4*)(G + aoff[i] + kn);
#pragma unroll
      for (int j = 0; j < 2; j++) pb[j] = *(const uint4*)(W2b + bbase + (size_t)j * 32 * II_ + kn);
    }
#pragma unroll
    for (int kk = 0; kk < 2; kk++) {
      bf16x8 af[4], bw[2];
#pragma unroll
      for (int fa = 0; fa < 4; fa++)
        af[fa] = *(const bf16x8*)&As[cur][(wr * 64 + fa * 16 + l15) * 72 + kk * 32 + lg * 8];
#pragma unroll
      for (int fb = 0; fb < 2; fb++)
        bw[fb] = *(const bf16x8*)&Bs[cur][(wc * 32 + fb * 16 + l15) * 72 + kk * 32 + lg * 8];
#pragma unroll
      for (int fa = 0; fa < 4; fa++)
#pragma unroll
        for (int fb = 0; fb < 2; fb++)
          acc[fa][fb] = __builtin_amdgcn_mfma_f32_16x16x32_bf16(af[fa], bw[fb], acc[fa][fb], 0, 0, 0);
    }
    if (t < II_ / 64 - 1) {
#pragma unroll
      for (int i = 0; i < 4; i++) *(uint4*)&As[cur ^ 1][(arow + 32 * i) * 72 + akg] = pa[i];
#pragma unroll
      for (int j = 0; j < 2; j++) *(uint4*)&Bs[cur ^ 1][(arow + 32 * j) * 72 + akg] = pb[j];
    }
    __syncthreads();
    cur ^= 1;
  }
#pragma unroll
  for (int fa = 0; fa < 4; fa++)
#pragma unroll
    for (int r = 0; r < 4; r++) {
      int prow = row0 + wr * 64 + fa * 16 + lg * 4 + r;
      if (prow < ne) {
        int p = pbase + prow;
        int ts = pairs_ts[p];
        float wgt = pairs_w[p];
#pragma unroll
        for (int fb = 0; fb < 2; fb++) {
          int col = col0 + wc * 32 + fb * 16 + l15;
          Pbuf[(size_t)ts * H_ + col] = wgt * acc[fa][fb][r];
        }
      }
    }
}

// ---------------- final: out = rmsnorm(resid + P0 + P1) ----------------
__global__ __launch_bounds__(256) void k_final(const float* __restrict__ resid, const float* __restrict__ Pbuf,
                                               const float* __restrict__ w, float* __restrict__ out) {
  int row = blockIdx.x;
  int tid = threadIdx.x;
  float4 a = ((const float4*)(resid + (size_t)row * H_))[tid];
  float4 p0 = ((const float4*)(Pbuf + (size_t)(2 * row) * H_))[tid];
  float4 p1 = ((const float4*)(Pbuf + (size_t)(2 * row + 1) * H_))[tid];
  float4 v;
  v.x = a.x + p0.x + p1.x; v.y = a.y + p0.y + p1.y; v.z = a.z + p0.z + p1.z; v.w = a.w + p0.w + p1.w;
  float ss = v.x * v.x + v.y * v.y + v.z * v.z + v.w * v.w;
#pragma unroll
  for (int off = 32; off; off >>= 1) ss += __shfl_xor(ss, off, 64);
  __shared__ float red[4];
  int lane = tid & 63, wid = tid >> 6;
  if (lane == 0) red[wid] = ss;
  __syncthreads();
  float tot = red[0] + red[1] + red[2] + red[3];
  float inv = rsqrtf(tot * (1.0f / H_) + 1e-5f);
  float4 wv = ((const float4*)w)[tid];
  float4 o;
  o.x = v.x * inv * wv.x; o.y = v.y * inv * wv.y; o.z = v.z * inv * wv.z; o.w = v.w * inv * wv.w;
  ((float4*)(out + (size_t)row * H_))[tid] = o;
}

extern "C" void kernel_launch(void* const* d_in, const int* in_sizes, int n_in,
                              void* d_out, int out_size, void* d_ws, size_t ws_size,
                              hipStream_t stream) {
  const float* x = (const float*)d_in[0];
  const int* pos = (const int*)d_in[1];
  const float* qkv_w = (const float*)d_in[2];
  const float* o_w = (const float*)d_in[3];
  const float* nin_w = (const float*)d_in[4];
  const float* npost_w = (const float*)d_in[5];
  const float* nnext_w = (const float*)d_in[6];
  const float* gate_w = (const float*)d_in[7];
  const float* w1 = (const float*)d_in[8];
  const float* w3 = (const float*)d_in[9];
  const float* w2 = (const float*)d_in[10];
  float* out = (float*)d_out;

  // ---- persistent region ----
  float* resid = (float*)d_ws;                       // T*H
  float* h2 = resid + (size_t)T_ * H_;               // T*H
  float* Pbuf = h2 + (size_t)T_ * H_;                // 2*T*H
  float* topw = Pbuf + (size_t)2 * T_ * H_;          // 2T
  float* pairsw = topw + T_ * 2;                     // 4096
  unsigned short* h2b = (unsigned short*)(pairsw + 4096);  // T*H
  unsigned short* G = h2b + (size_t)T_ * H_;         // 2*T*II
  int* topi = (int*)(G + (size_t)2 * T_ * II_);      // 2T
  int* ctrl = topi + T_ * 2;
  int* counts = ctrl;
  int* counts2 = ctrl + 8;
  int* offsets = ctrl + 16;
  int* pairs_ts = ctrl + 24;                         // 4096
  char* trans = (char*)(pairs_ts + 4096);
  trans = (char*)(((uintptr_t)trans + 255) & ~(uintptr_t)255);

  // ---- transient: attention phase ----
  float* h_in = (float*)trans;                       // T*H
  float* qkvb = h_in + (size_t)T_ * H_;              // T*1536
  float* attnb = qkvb + (size_t)T_ * 1536;           // T*HQ*D
  float* ct = attnb + (size_t)T_ * HQ_ * D_;         // T*32
  float* st = ct + (size_t)T_ * 32;                  // T*32
  unsigned short* uu = (unsigned short*)(st + (size_t)T_ * 32);
  unsigned short* Qhi = uu;  uu += (size_t)HQ_ * T_ * D_;
  unsigned short* Qlo = uu;  uu += (size_t)HQ_ * T_ * D_;
  unsigned short* Khi = uu;  uu += (size_t)HK_ * T_ * D_;
  unsigned short* Klo = uu;  uu += (size_t)HK_ * T_ * D_;
  unsigned short* Vthi = uu; uu += (size_t)HK_ * D_ * T_;
  unsigned short* Vtlo = uu; uu += (size_t)HK_ * D_ * T_;

  // ---- transient: MoE phase (aliases attention transients; conv runs after attention is done) ----
  unsigned short* W1b = (unsigned short*)trans;                 // E*I*H
  unsigned short* W3b = W1b + (size_t)NE_ * II_ * H_;
  unsigned short* W2b = W3b + (size_t)NE_ * II_ * H_;

  const int WCNT8 = (NE_ * II_ * H_) / 8;

  hipMemsetAsync(ctrl, 0, 64, stream);  // counts + counts2
  k_rmsnorm<<<T_, 256, 0, stream>>>(x, nin_w, h_in, (unsigned short*)nullptr);
  k_sgemm_nt<0><<<dim3((HQ_ + 2 * HK_) * D_ / 64, T_ / 64), 256, 0, stream>>>(h_in, qkv_w, qkvb, nullptr, T_,
                                                                              (HQ_ + 2 * HK_) * D_, H_);
  k_rope_table<<<T_ * 32 / 256, 256, 0, stream>>>(pos, ct, st);
  k_rope_prep<<<T_, 256, 0, stream>>>(qkvb, ct, st, Qhi, Qlo, Khi, Klo);
  k_vtrans<<<dim3(T_ / 64, HK_), 256, 0, stream>>>(qkvb, Vthi, Vtlo);
  k_attn_mfma<<<dim3(512), 256, 0, stream>>>(Qhi, Qlo, Khi, Klo, Vthi, Vtlo, attnb);
  k_sgemm_nt<1><<<dim3(H_ / 64, T_ / 64), 256, 0, stream>>>(attnb, o_w, resid, x, T_, H_, HQ_ * D_);
  k_rmsnorm<<<T_, 256, 0, stream>>>(resid, npost_w, h2, h2b);
  k_router<<<T_ / 4, 256, 0, stream>>>(h2, gate_w, topi, topw, counts);
  k_scan<<<1, 64, 0, stream>>>(counts, offsets);
  k_build<<<T_ / 256, 256, 0, stream>>>(topi, topw, offsets, counts2, pairs_ts, pairsw);
  // weight pre-conversion (attention transients are dead now)
  k_conv<<<2048, 256, 0, stream>>>(w1, W1b, WCNT8);
  k_conv<<<2048, 256, 0, stream>>>(w3, W3b, WCNT8);
  k_conv<<<2048, 256, 0, stream>>>(w2, W2b, WCNT8);
  k_moe_up<<<dim3(II_ / 64, T_ / 128, NE_), 256, 0, stream>>>(h2b, W1b, W3b, pairs_ts, offsets, counts, G);
  k_moe_down<<<dim3(H_ / 64, T_ / 128, NE_), 256, 0, stream>>>(G, W2b, pairs_ts, pairsw, offsets, counts, Pbuf);
  k_final<<<T_, 256, 0, stream>>>(resid, Pbuf, nnext_w, out);
}

// Round 5
// 551.074 us; speedup vs baseline: 1.6343x; 1.0751x over previous
//
#include <hip/hip_runtime.h>
#include <hip/hip_bf16.h>
#include <math.h>

#define T_ 2048
#define H_ 1024
#define HQ_ 16
#define HK_ 4
#define D_ 64
#define NE_ 8
#define II_ 2048

typedef __attribute__((ext_vector_type(8))) short bf16x8;
typedef __attribute__((ext_vector_type(8))) unsigned short u16x8;
typedef __attribute__((ext_vector_type(4))) float f32x4;

__device__ __forceinline__ unsigned short f2bf(float f) {
  unsigned int u = __float_as_uint(f);
  return (unsigned short)((u + 0x7fffu + ((u >> 16) & 1u)) >> 16);
}
__device__ __forceinline__ float bf2f(unsigned short h) {
  return __uint_as_float((unsigned int)h << 16);
}

// ---------------- rmsnorm (fp32 in, fp32 out + optional bf16 out) ----------------
__global__ __launch_bounds__(256) void k_rmsnorm(const float* __restrict__ x, const float* __restrict__ w,
                                                 float* __restrict__ outf, unsigned short* __restrict__ outb) {
  int row = blockIdx.x;
  int tid = threadIdx.x;
  float4 v = ((const float4*)(x + (size_t)row * H_))[tid];
  float ss = v.x * v.x + v.y * v.y + v.z * v.z + v.w * v.w;
#pragma unroll
  for (int off = 32; off; off >>= 1) ss += __shfl_xor(ss, off, 64);
  __shared__ float red[4];
  int lane = tid & 63, wid = tid >> 6;
  if (lane == 0) red[wid] = ss;
  __syncthreads();
  float tot = red[0] + red[1] + red[2] + red[3];
  float inv = rsqrtf(tot * (1.0f / H_) + 1e-5f);
  float4 wv = ((const float4*)w)[tid];
  float4 o;
  o.x = v.x * inv * wv.x; o.y = v.y * inv * wv.y; o.z = v.z * inv * wv.z; o.w = v.w * inv * wv.w;
  ((float4*)(outf + (size_t)row * H_))[tid] = o;
  if (outb) {
    ushort4 b; b.x = f2bf(o.x); b.y = f2bf(o.y); b.z = f2bf(o.z); b.w = f2bf(o.w);
    ((ushort4*)(outb + (size_t)row * H_))[tid] = b;
  }
}

// ---------------- rmsnorm writing expanded bf16x3 A' = [hi|hi|lo] along K'=3H ----------------
__global__ __launch_bounds__(256) void k_rmsnorm_split(const float* __restrict__ x, const float* __restrict__ w,
                                                       unsigned short* __restrict__ Aq) {
  int row = blockIdx.x;
  int tid = threadIdx.x;
  float4 v = ((const float4*)(x + (size_t)row * H_))[tid];
  float ss = v.x * v.x + v.y * v.y + v.z * v.z + v.w * v.w;
#pragma unroll
  for (int off = 32; off; off >>= 1) ss += __shfl_xor(ss, off, 64);
  __shared__ float red[4];
  int lane = tid & 63, wid = tid >> 6;
  if (lane == 0) red[wid] = ss;
  __syncthreads();
  float tot = red[0] + red[1] + red[2] + red[3];
  float inv = rsqrtf(tot * (1.0f / H_) + 1e-5f);
  float4 wv = ((const float4*)w)[tid];
  float4 o;
  o.x = v.x * inv * wv.x; o.y = v.y * inv * wv.y; o.z = v.z * inv * wv.z; o.w = v.w * inv * wv.w;
  ushort4 hi, lo;
  hi.x = f2bf(o.x); hi.y = f2bf(o.y); hi.z = f2bf(o.z); hi.w = f2bf(o.w);
  lo.x = f2bf(o.x - bf2f(hi.x)); lo.y = f2bf(o.y - bf2f(hi.y));
  lo.z = f2bf(o.z - bf2f(hi.z)); lo.w = f2bf(o.w - bf2f(hi.w));
  size_t base = (size_t)row * (3 * H_) + tid * 4;
  *(ushort4*)(Aq + base) = hi;
  *(ushort4*)(Aq + base + H_) = hi;
  *(ushort4*)(Aq + base + 2 * H_) = lo;
}

// ---------------- weight split: W[N][K] fp32 -> W'[N][3K] bf16 = [hi|lo|hi] ----------------
__global__ __launch_bounds__(256) void k_wsplit(const float* __restrict__ in, unsigned short* __restrict__ out,
                                                int K, int n8total) {
  int stride = gridDim.x * 256;
  int kc8 = K >> 3;
  for (int i = blockIdx.x * 256 + threadIdx.x; i < n8total; i += stride) {
    int n = i / kc8, kc = (i - n * kc8) * 8;
    const float4* p = (const float4*)(in + (size_t)n * K + kc);
    float4 a = p[0], b = p[1];
    u16x8 hi, lo;
    hi[0] = f2bf(a.x); hi[1] = f2bf(a.y); hi[2] = f2bf(a.z); hi[3] = f2bf(a.w);
    hi[4] = f2bf(b.x); hi[5] = f2bf(b.y); hi[6] = f2bf(b.z); hi[7] = f2bf(b.w);
    lo[0] = f2bf(a.x - bf2f(hi[0])); lo[1] = f2bf(a.y - bf2f(hi[1]));
    lo[2] = f2bf(a.z - bf2f(hi[2])); lo[3] = f2bf(a.w - bf2f(hi[3]));
    lo[4] = f2bf(b.x - bf2f(hi[4])); lo[5] = f2bf(b.y - bf2f(hi[5]));
    lo[6] = f2bf(b.z - bf2f(hi[6])); lo[7] = f2bf(b.w - bf2f(hi[7]));
    size_t ob = (size_t)n * 3 * K + kc;
    *(u16x8*)(out + ob) = hi;
    *(u16x8*)(out + ob + K) = lo;
    *(u16x8*)(out + ob + 2 * K) = hi;
  }
}

// ---------------- bf16 GEMM (expanded-K bf16x3): C[M][N] = A'[M][K3] @ B'[N][K3]^T (+ADD) ----------------
template <int ADD>
__global__ __launch_bounds__(256) void k_hgemm(const unsigned short* __restrict__ A, const unsigned short* __restrict__ B,
                                               float* __restrict__ C, const float* __restrict__ addsrc,
                                               int N, int K3) {
  int m0 = blockIdx.y * 128, n0 = blockIdx.x * 64;
  __shared__ unsigned short As[2][128 * 72];
  __shared__ unsigned short Bs[2][64 * 72];
  int tid = threadIdx.x, lane = tid & 63, wid = tid >> 6;
  int wr = wid >> 1, wc = wid & 1;
  int l15 = lane & 15, lg = lane >> 4;
  int arow = tid >> 3, akg = (tid & 7) * 8;

  size_t aoff[4];
#pragma unroll
  for (int i = 0; i < 4; i++) aoff[i] = (size_t)(m0 + arow + 32 * i) * K3 + akg;
  size_t boff[2];
#pragma unroll
  for (int j = 0; j < 2; j++) boff[j] = (size_t)(n0 + arow + 32 * j) * K3 + akg;

  f32x4 acc[4][2];
  f32x4 z = {0.f, 0.f, 0.f, 0.f};
#pragma unroll
  for (int a = 0; a < 4; a++)
#pragma unroll
    for (int b = 0; b < 2; b++) acc[a][b] = z;

  uint4 pa[4], pb[2];
#pragma unroll
  for (int i = 0; i < 4; i++) pa[i] = *(const uint4*)(A + aoff[i]);
#pragma unroll
  for (int j = 0; j < 2; j++) pb[j] = *(const uint4*)(B + boff[j]);
#pragma unroll
  for (int i = 0; i < 4; i++) *(uint4*)&As[0][(arow + 32 * i) * 72 + akg] = pa[i];
#pragma unroll
  for (int j = 0; j < 2; j++) *(uint4*)&Bs[0][(arow + 32 * j) * 72 + akg] = pb[j];
  __syncthreads();
  int cur = 0;
  int nt = K3 / 64;
  for (int t = 0; t < nt; ++t) {
    if (t < nt - 1) {
      int kn = (t + 1) * 64;
#pragma unroll
      for (int i = 0; i < 4; i++) pa[i] = *(const uint4*)(A + aoff[i] + kn);
#pragma unroll
      for (int j = 0; j < 2; j++) pb[j] = *(const uint4*)(B + boff[j] + kn);
    }
#pragma unroll
    for (int kk = 0; kk < 2; kk++) {
      bf16x8 af[4], bw[2];
#pragma unroll
      for (int fa = 0; fa < 4; fa++)
        af[fa] = *(const bf16x8*)&As[cur][(wr * 64 + fa * 16 + l15) * 72 + kk * 32 + lg * 8];
#pragma unroll
      for (int fb = 0; fb < 2; fb++)
        bw[fb] = *(const bf16x8*)&Bs[cur][(wc * 32 + fb * 16 + l15) * 72 + kk * 32 + lg * 8];
#pragma unroll
      for (int fa = 0; fa < 4; fa++)
#pragma unroll
        for (int fb = 0; fb < 2; fb++)
          acc[fa][fb] = __builtin_amdgcn_mfma_f32_16x16x32_bf16(af[fa], bw[fb], acc[fa][fb], 0, 0, 0);
    }
    if (t < nt - 1) {
#pragma unroll
      for (int i = 0; i < 4; i++) *(uint4*)&As[cur ^ 1][(arow + 32 * i) * 72 + akg] = pa[i];
#pragma unroll
      for (int j = 0; j < 2; j++) *(uint4*)&Bs[cur ^ 1][(arow + 32 * j) * 72 + akg] = pb[j];
    }
    __syncthreads();
    cur ^= 1;
  }
#pragma unroll
  for (int fa = 0; fa < 4; fa++)
#pragma unroll
    for (int r = 0; r < 4; r++) {
      int row = m0 + wr * 64 + fa * 16 + lg * 4 + r;
#pragma unroll
      for (int fb = 0; fb < 2; fb++) {
        int col = n0 + wc * 32 + fb * 16 + l15;
        float v = acc[fa][fb][r];
        if (ADD) v += addsrc[(size_t)row * N + col];
        C[(size_t)row * N + col] = v;
      }
    }
}

// ---------------- RoPE cos/sin table (matches np float32 angle bits) ----------------
__global__ __launch_bounds__(256) void k_rope_table(const int* __restrict__ pos, float* __restrict__ ct,
                                                    float* __restrict__ st) {
  int idx = blockIdx.x * 256 + threadIdx.x;  // T*32
  int t = idx >> 5, i = idx & 31;
  float p = (float)pow(10000.0, (double)i / 32.0);
  float freq = 1.0f / p;
  float ang = (float)pos[t] * freq;
  ct[idx] = cosf(ang);
  st[idx] = sinf(ang);
}

// ---------------- RoPE apply + bf16 hi/lo split ----------------
__global__ __launch_bounds__(256) void k_rope_prep(const float* __restrict__ qkv, const float* __restrict__ ct,
                                                   const float* __restrict__ st, unsigned short* __restrict__ Qhi,
                                                   unsigned short* __restrict__ Qlo, unsigned short* __restrict__ Khi,
                                                   unsigned short* __restrict__ Klo) {
  int t = blockIdx.x, tid = threadIdx.x;
  const float* row = qkv + (size_t)t * 1536;
#pragma unroll 2
  for (int it = tid; it < 512; it += 256) {
    int h = it >> 5, i = it & 31;
    float c = ct[t * 32 + i], s = st[t * 32 + i];
    float x1 = row[h * 64 + i], x2 = row[h * 64 + i + 32];
    float a = (x1 * c - x2 * s) * 0.125f;
    float b = (x2 * c + x1 * s) * 0.125f;
    size_t base = ((size_t)h * T_ + t) * 64 + i;
    unsigned short ah = f2bf(a), bh = f2bf(b);
    Qhi[base] = ah; Qhi[base + 32] = bh;
    Qlo[base] = f2bf(a - bf2f(ah));
    Qlo[base + 32] = f2bf(b - bf2f(bh));
  }
  if (tid < 128) {
    int h = tid >> 5, i = tid & 31;
    float c = ct[t * 32 + i], s = st[t * 32 + i];
    float x1 = row[1024 + h * 64 + i], x2 = row[1024 + h * 64 + i + 32];
    float a = x1 * c - x2 * s;
    float b = x2 * c + x1 * s;
    size_t base = ((size_t)h * T_ + t) * 64 + i;
    unsigned short ah = f2bf(a), bh = f2bf(b);
    Khi[base] = ah; Khi[base + 32] = bh;
    Klo[base] = f2bf(a - bf2f(ah));
    Klo[base + 32] = f2bf(b - bf2f(bh));
  }
}

// ---------------- V transpose + split: Vthi/Vtlo [kvh][d][t] ----------------
__global__ __launch_bounds__(256) void k_vtrans(const float* __restrict__ qkv, unsigned short* __restrict__ Vthi,
                                                unsigned short* __restrict__ Vtlo) {
  int t0 = blockIdx.x * 64, h = blockIdx.y;
  __shared__ float tile[64][65];
  int tid = threadIdx.x;
  int c = tid & 63, w = tid >> 6;
  for (int r = w; r < 64; r += 4)
    tile[r][c] = qkv[(size_t)(t0 + r) * 1536 + 1280 + h * 64 + c];
  __syncthreads();
  for (int d = w; d < 64; d += 4) {
    float v = tile[c][d];
    unsigned short hi = f2bf(v);
    size_t idx = ((size_t)h * 64 + d) * T_ + t0 + c;
    Vthi[idx] = hi;
    Vtlo[idx] = f2bf(v - bf2f(hi));
  }
}

// ---------------- flash attention, bf16x3 split MFMA; epilogue writes expanded A'o ----------------
__global__ __launch_bounds__(256) void k_attn_mfma(const unsigned short* __restrict__ Qhi,
                                                   const unsigned short* __restrict__ Qlo,
                                                   const unsigned short* __restrict__ Khi,
                                                   const unsigned short* __restrict__ Klo,
                                                   const unsigned short* __restrict__ Vthi,
                                                   const unsigned short* __restrict__ Vtlo,
                                                   unsigned short* __restrict__ Ao) {
  int bid = blockIdx.x;
  int kk = bid >> 4;
  int head = bid & 15;
  int qidx = (kk < 16) ? (31 - kk) : (kk - 16);
  int qb = qidx * 64;
  int kvh = head >> 2;
  int tid = threadIdx.x, lane = tid & 63, w = tid >> 6;
  int l15 = lane & 15, lg = lane >> 4;

  __shared__ unsigned short KsH[64 * 72], KsL[64 * 72];
  __shared__ unsigned short VsH[64 * 72], VsL[64 * 72];
  __shared__ unsigned short PsH[64 * 72], PsL[64 * 72];

  bf16x8 qh[2], ql[2];
  {
    size_t qbase = ((size_t)head * T_ + qb + w * 16 + l15) * 64 + lg * 8;
    qh[0] = *(const bf16x8*)(Qhi + qbase);
    qh[1] = *(const bf16x8*)(Qhi + qbase + 32);
    ql[0] = *(const bf16x8*)(Qlo + qbase);
    ql[1] = *(const bf16x8*)(Qlo + qbase + 32);
  }
  f32x4 z = {0.f, 0.f, 0.f, 0.f};
  f32x4 Oa[4];
  float mrow[4], lrow[4];
#pragma unroll
  for (int r = 0; r < 4; r++) { mrow[r] = -1e30f; lrow[r] = 0.f; }
#pragma unroll
  for (int dg = 0; dg < 4; dg++) Oa[dg] = z;

  for (int jb = 0; jb <= qb; jb += 64) {
    __syncthreads();
    for (int c = tid; c < 512; c += 256) {
      int r = c >> 3, g = (c & 7) * 8;
      size_t kgl = ((size_t)kvh * T_ + jb + r) * 64 + g;
      size_t vgl = ((size_t)kvh * 64 + r) * T_ + jb + g;
      *(uint4*)&KsH[r * 72 + g] = *(const uint4*)(Khi + kgl);
      *(uint4*)&KsL[r * 72 + g] = *(const uint4*)(Klo + kgl);
      *(uint4*)&VsH[r * 72 + g] = *(const uint4*)(Vthi + vgl);
      *(uint4*)&VsL[r * 72 + g] = *(const uint4*)(Vtlo + vgl);
    }
    __syncthreads();

    f32x4 sc[4];
    sc[0] = z; sc[1] = z; sc[2] = z; sc[3] = z;
#pragma unroll
    for (int kg = 0; kg < 4; kg++) {
      int ba = (kg * 16 + l15) * 72 + lg * 8;
      bf16x8 bh0 = *(const bf16x8*)&KsH[ba];
      bf16x8 bh1 = *(const bf16x8*)&KsH[ba + 32];
      bf16x8 bl0 = *(const bf16x8*)&KsL[ba];
      bf16x8 bl1 = *(const bf16x8*)&KsL[ba + 32];
      sc[kg] = __builtin_amdgcn_mfma_f32_16x16x32_bf16(qh[0], bh0, sc[kg], 0, 0, 0);
      sc[kg] = __builtin_amdgcn_mfma_f32_16x16x32_bf16(qh[1], bh1, sc[kg], 0, 0, 0);
      sc[kg] = __builtin_amdgcn_mfma_f32_16x16x32_bf16(qh[0], bl0, sc[kg], 0, 0, 0);
      sc[kg] = __builtin_amdgcn_mfma_f32_16x16x32_bf16(qh[1], bl1, sc[kg], 0, 0, 0);
      sc[kg] = __builtin_amdgcn_mfma_f32_16x16x32_bf16(ql[0], bh0, sc[kg], 0, 0, 0);
      sc[kg] = __builtin_amdgcn_mfma_f32_16x16x32_bf16(ql[1], bh1, sc[kg], 0, 0, 0);
    }
    if (jb == qb) {
      int rb = w * 16 + lg * 4;
#pragma unroll
      for (int kg = 0; kg < 4; kg++) {
        int col = kg * 16 + l15;
#pragma unroll
        for (int r = 0; r < 4; r++)
          if (col > rb + r) sc[kg][r] = -1e30f;
      }
    }
#pragma unroll
    for (int r = 0; r < 4; r++) {
      float mt = fmaxf(fmaxf(sc[0][r], sc[1][r]), fmaxf(sc[2][r], sc[3][r]));
      mt = fmaxf(mt, __shfl_xor(mt, 1, 64));
      mt = fmaxf(mt, __shfl_xor(mt, 2, 64));
      mt = fmaxf(mt, __shfl_xor(mt, 4, 64));
      mt = fmaxf(mt, __shfl_xor(mt, 8, 64));
      float mnew = fmaxf(mrow[r], mt);
      float corr = __expf(mrow[r] - mnew);
      mrow[r] = mnew;
      float s = 0.f;
#pragma unroll
      for (int kg = 0; kg < 4; kg++) {
        float p = __expf(sc[kg][r] - mnew);
        sc[kg][r] = p;
        s += p;
      }
      s += __shfl_xor(s, 1, 64);
      s += __shfl_xor(s, 2, 64);
      s += __shfl_xor(s, 4, 64);
      s += __shfl_xor(s, 8, 64);
      lrow[r] = lrow[r] * corr + s;
      // per-ROW rescale (Oa[dg] components are 4 different rows)
#pragma unroll
      for (int dg = 0; dg < 4; dg++) Oa[dg][r] *= corr;
    }
    {
      int rb = w * 16 + lg * 4;
#pragma unroll
      for (int kg = 0; kg < 4; kg++) {
        int col = kg * 16 + l15;
#pragma unroll
        for (int r = 0; r < 4; r++) {
          float p = sc[kg][r];
          unsigned short ph = f2bf(p);
          PsH[(rb + r) * 72 + col] = ph;
          PsL[(rb + r) * 72 + col] = f2bf(p - bf2f(ph));
        }
      }
    }
    {
      int ab = (w * 16 + l15) * 72 + lg * 8;
      bf16x8 ph0 = *(const bf16x8*)&PsH[ab];
      bf16x8 ph1 = *(const bf16x8*)&PsH[ab + 32];
      bf16x8 pl0 = *(const bf16x8*)&PsL[ab];
      bf16x8 pl1 = *(const bf16x8*)&PsL[ab + 32];
#pragma unroll
      for (int dg = 0; dg < 4; dg++) {
        int vb = (dg * 16 + l15) * 72 + lg * 8;
        bf16x8 vh0 = *(const bf16x8*)&VsH[vb];
        bf16x8 vh1 = *(const bf16x8*)&VsH[vb + 32];
        bf16x8 vl0 = *(const bf16x8*)&VsL[vb];
        bf16x8 vl1 = *(const bf16x8*)&VsL[vb + 32];
        Oa[dg] = __builtin_amdgcn_mfma_f32_16x16x32_bf16(ph0, vh0, Oa[dg], 0, 0, 0);
        Oa[dg] = __builtin_amdgcn_mfma_f32_16x16x32_bf16(ph1, vh1, Oa[dg], 0, 0, 0);
        Oa[dg] = __builtin_amdgcn_mfma_f32_16x16x32_bf16(ph0, vl0, Oa[dg], 0, 0, 0);
        Oa[dg] = __builtin_amdgcn_mfma_f32_16x16x32_bf16(ph1, vl1, Oa[dg], 0, 0, 0);
        Oa[dg] = __builtin_amdgcn_mfma_f32_16x16x32_bf16(pl0, vh0, Oa[dg], 0, 0, 0);
        Oa[dg] = __builtin_amdgcn_mfma_f32_16x16x32_bf16(pl1, vh1, Oa[dg], 0, 0, 0);
      }
    }
  }
#pragma unroll
  for (int r = 0; r < 4; r++) {
    float inv = 1.0f / lrow[r];
    size_t rb2 = (size_t)(qb + w * 16 + lg * 4 + r) * 3072 + head * 64;
#pragma unroll
    for (int dg = 0; dg < 4; dg++) {
      float v = Oa[dg][r] * inv;
      unsigned short hi = f2bf(v);
      unsigned short lo = f2bf(v - bf2f(hi));
      Ao[rb2 + dg * 16 + l15] = hi;
      Ao[rb2 + 1024 + dg * 16 + l15] = hi;
      Ao[rb2 + 2048 + dg * 16 + l15] = lo;
    }
  }
}

// ---------------- router ----------------
__global__ __launch_bounds__(256) void k_router(const float* __restrict__ h2, const float* __restrict__ gw,
                                                int* __restrict__ topi, float* __restrict__ topw,
                                                int* __restrict__ counts) {
  int wid = threadIdx.x >> 6, lane = threadIdx.x & 63;
  int t = blockIdx.x * 4 + wid;
  const float* hr = h2 + (size_t)t * H_;
  float hv[16];
#pragma unroll
  for (int i = 0; i < 16; i++) hv[i] = hr[lane + 64 * i];
  float le[8];
#pragma unroll
  for (int e = 0; e < 8; e++) {
    const float* g = gw + (size_t)e * H_;
    float acc = 0.f;
#pragma unroll
    for (int i = 0; i < 16; i++) acc += hv[i] * g[lane + 64 * i];
#pragma unroll
    for (int off = 32; off; off >>= 1) acc += __shfl_xor(acc, off, 64);
    le[e] = acc;
  }
  if (lane == 0) {
    int i0 = 0;
#pragma unroll
    for (int e = 1; e < 8; e++)
      if (le[e] > le[i0]) i0 = e;
    int i1 = (i0 == 0) ? 1 : 0;
#pragma unroll
    for (int e = 0; e < 8; e++) {
      if (e == i0) continue;
      if (le[e] > le[i1]) i1 = e;
    }
    float w1r = expf(le[i1] - le[i0]);
    float denom = 1.0f + w1r;
    topi[t * 2 + 0] = i0;
    topi[t * 2 + 1] = i1;
    topw[t * 2 + 0] = 1.0f / denom;
    topw[t * 2 + 1] = w1r / denom;
    atomicAdd(&counts[i0], 1);
    atomicAdd(&counts[i1], 1);
  }
}

__global__ void k_scan(const int* __restrict__ counts, int* __restrict__ offsets) {
  if (threadIdx.x == 0 && blockIdx.x == 0) {
    int off = 0;
    for (int e = 0; e < NE_; e++) { offsets[e] = off; off += counts[e]; }
  }
}

__global__ __launch_bounds__(256) void k_build(const int* __restrict__ topi, const float* __restrict__ topw,
                                               const int* __restrict__ offsets, int* __restrict__ counts2,
                                               int* __restrict__ pairs_ts, float* __restrict__ pairs_w) {
  int t = blockIdx.x * 256 + threadIdx.x;
#pragma unroll
  for (int s = 0; s < 2; s++) {
    int e = topi[t * 2 + s];
    int slot = atomicAdd(&counts2[e], 1);
    int p = offsets[e] + slot;
    pairs_ts[p] = t * 2 + s;
    pairs_w[p] = topw[t * 2 + s];
  }
}

// ---------------- fp32 -> bf16 bulk convert ----------------
__global__ __launch_bounds__(256) void k_conv(const float* __restrict__ in, unsigned short* __restrict__ out, int n8) {
  int stride = gridDim.x * 256;
  for (int i = blockIdx.x * 256 + threadIdx.x; i < n8; i += stride) {
    const float4* p = (const float4*)in + (size_t)i * 2;
    float4 a = p[0], b = p[1];
    u16x8 t;
    t[0] = f2bf(a.x); t[1] = f2bf(a.y); t[2] = f2bf(a.z); t[3] = f2bf(a.w);
    t[4] = f2bf(b.x); t[5] = f2bf(b.y); t[6] = f2bf(b.z); t[7] = f2bf(b.w);
    *((u16x8*)out + i) = t;
  }
}

// ---------------- MoE up: 128x64 tile, BK=64, dbuf LDS, bf16 weights ----------------
__global__ __launch_bounds__(256) void k_moe_up(const unsigned short* __restrict__ h2b, const unsigned short* __restrict__ W1b,
                                                const unsigned short* __restrict__ W3b, const int* __restrict__ pairs_ts,
                                                const int* __restrict__ offsets, const int* __restrict__ counts,
                                                unsigned short* __restrict__ G) {
  int e = blockIdx.z;
  int ne = counts[e];
  int row0 = blockIdx.y * 128;
  if (row0 >= ne) return;
  int col0 = blockIdx.x * 64;
  int pbase = offsets[e];
  __shared__ unsigned short As[2][128 * 72];
  __shared__ unsigned short B1s[2][64 * 72];
  __shared__ unsigned short B2s[2][64 * 72];
  int tid = threadIdx.x, lane = tid & 63, wid = tid >> 6;
  int wr = wid >> 1, wc = wid & 1;
  int l15 = lane & 15, lg = lane >> 4;
  int arow = tid >> 3, akg = (tid & 7) * 8;

  int aoff[4];
#pragma unroll
  for (int i = 0; i < 4; i++) {
    int grow = row0 + arow + 32 * i;
    int tok = (grow < ne) ? (pairs_ts[pbase + grow] >> 1) : 0;
    aoff[i] = tok * H_ + akg;
  }
  size_t bbase = ((size_t)e * II_ + col0 + arow) * H_ + akg;

  f32x4 acc1[4][2], acc2[4][2];
  f32x4 z = {0.f, 0.f, 0.f, 0.f};
#pragma unroll
  for (int a = 0; a < 4; a++)
#pragma unroll
    for (int b = 0; b < 2; b++) { acc1[a][b] = z; acc2[a][b] = z; }

  uint4 pa[4], pb1[2], pb2[2];
#pragma unroll
  for (int i = 0; i < 4; i++) pa[i] = *(const uint4*)(h2b + aoff[i]);
#pragma unroll
  for (int j = 0; j < 2; j++) {
    pb1[j] = *(const uint4*)(W1b + bbase + (size_t)j * 32 * H_);
    pb2[j] = *(const uint4*)(W3b + bbase + (size_t)j * 32 * H_);
  }
#pragma unroll
  for (int i = 0; i < 4; i++) *(uint4*)&As[0][(arow + 32 * i) * 72 + akg] = pa[i];
#pragma unroll
  for (int j = 0; j < 2; j++) {
    *(uint4*)&B1s[0][(arow + 32 * j) * 72 + akg] = pb1[j];
    *(uint4*)&B2s[0][(arow + 32 * j) * 72 + akg] = pb2[j];
  }
  __syncthreads();
  int cur = 0;
  for (int t = 0; t < H_ / 64; ++t) {
    if (t < H_ / 64 - 1) {
      int kn = (t + 1) * 64;
#pragma unroll
      for (int i = 0; i < 4; i++) pa[i] = *(const uint4*)(h2b + aoff[i] + kn);
#pragma unroll
      for (int j = 0; j < 2; j++) {
        pb1[j] = *(const uint4*)(W1b + bbase + (size_t)j * 32 * H_ + kn);
        pb2[j] = *(const uint4*)(W3b + bbase + (size_t)j * 32 * H_ + kn);
      }
    }
#pragma unroll
    for (int kk = 0; kk < 2; kk++) {
      bf16x8 af[4], b1f[2], b2f[2];
#pragma unroll
      for (int fa = 0; fa < 4; fa++)
        af[fa] = *(const bf16x8*)&As[cur][(wr * 64 + fa * 16 + l15) * 72 + kk * 32 + lg * 8];
#pragma unroll
      for (int fb = 0; fb < 2; fb++) {
        b1f[fb] = *(const bf16x8*)&B1s[cur][(wc * 32 + fb * 16 + l15) * 72 + kk * 32 + lg * 8];
        b2f[fb] = *(const bf16x8*)&B2s[cur][(wc * 32 + fb * 16 + l15) * 72 + kk * 32 + lg * 8];
      }
#pragma unroll
      for (int fa = 0; fa < 4; fa++)
#pragma unroll
        for (int fb = 0; fb < 2; fb++) {
          acc1[fa][fb] = __builtin_amdgcn_mfma_f32_16x16x32_bf16(af[fa], b1f[fb], acc1[fa][fb], 0, 0, 0);
          acc2[fa][fb] = __builtin_amdgcn_mfma_f32_16x16x32_bf16(af[fa], b2f[fb], acc2[fa][fb], 0, 0, 0);
        }
    }
    if (t < H_ / 64 - 1) {
#pragma unroll
      for (int i = 0; i < 4; i++) *(uint4*)&As[cur ^ 1][(arow + 32 * i) * 72 + akg] = pa[i];
#pragma unroll
      for (int j = 0; j < 2; j++) {
        *(uint4*)&B1s[cur ^ 1][(arow + 32 * j) * 72 + akg] = pb1[j];
        *(uint4*)&B2s[cur ^ 1][(arow + 32 * j) * 72 + akg] = pb2[j];
      }
    }
    __syncthreads();
    cur ^= 1;
  }
#pragma unroll
  for (int fa = 0; fa < 4; fa++)
#pragma unroll
    for (int r = 0; r < 4; r++) {
      int prow = row0 + wr * 64 + fa * 16 + lg * 4 + r;
      if (prow < ne) {
#pragma unroll
        for (int fb = 0; fb < 2; fb++) {
          int icol = col0 + wc * 32 + fb * 16 + l15;
          float h1 = acc1[fa][fb][r], h3 = acc2[fa][fb][r];
          float g = h1 / (1.0f + __expf(-h1)) * h3;
          G[(size_t)(pbase + prow) * II_ + icol] = f2bf(g);
        }
      }
    }
}

// ---------------- MoE down: 128x64 tile, BK=64, dbuf LDS, bf16 W2 ----------------
__global__ __launch_bounds__(256) void k_moe_down(const unsigned short* __restrict__ G, const unsigned short* __restrict__ W2b,
                                                  const int* __restrict__ pairs_ts, const float* __restrict__ pairs_w,
                                                  const int* __restrict__ offsets, const int* __restrict__ counts,
                                                  float* __restrict__ Pbuf) {
  int e = blockIdx.z;
  int ne = counts[e];
  int row0 = blockIdx.y * 128;
  if (row0 >= ne) return;
  int col0 = blockIdx.x * 64;
  int pbase = offsets[e];
  __shared__ unsigned short As[2][128 * 72];
  __shared__ unsigned short Bs[2][64 * 72];
  int tid = threadIdx.x, lane = tid & 63, wid = tid >> 6;
  int wr = wid >> 1, wc = wid & 1;
  int l15 = lane & 15, lg = lane >> 4;
  int arow = tid >> 3, akg = (tid & 7) * 8;

  int aoff[4];
#pragma unroll
  for (int i = 0; i < 4; i++) {
    int grow = row0 + arow + 32 * i;
    int p = pbase + ((grow < ne) ? grow : 0);
    aoff[i] = p * II_ + akg;
  }
  size_t bbase = ((size_t)e * H_ + col0 + arow) * II_ + akg;

  f32x4 acc[4][2];
  f32x4 z = {0.f, 0.f, 0.f, 0.f};
#pragma unroll
  for (int a = 0; a < 4; a++)
#pragma unroll
    for (int b = 0; b < 2; b++) acc[a][b] = z;

  uint4 pa[4], pb[2];
#pragma unroll
  for (int i = 0; i < 4; i++) pa[i] = *(const uint4*)(G + aoff[i]);
#pragma unroll
  for (int j = 0; j < 2; j++) pb[j] = *(const uint4*)(W2b + bbase + (size_t)j * 32 * II_);
#pragma unroll
  for (int i = 0; i < 4; i++) *(uint4*)&As[0][(arow + 32 * i) * 72 + akg] = pa[i];
#pragma unroll
  for (int j = 0; j < 2; j++) *(uint4*)&Bs[0][(arow + 32 * j) * 72 + akg] = pb[j];
  __syncthreads();
  int cur = 0;
  for (int t = 0; t < II_ / 64; ++t) {
    if (t < II_ / 64 - 1) {
      int kn = (t + 1) * 64;
#pragma unroll
      for (int i = 0; i < 4; i++) pa[i] = *(const uint4*)(G + aoff[i] + kn);
#pragma unroll
      for (int j = 0; j < 2; j++) pb[j] = *(const uint4*)(W2b + bbase + (size_t)j * 32 * II_ + kn);
    }
#pragma unroll
    for (int kk = 0; kk < 2; kk++) {
      bf16x8 af[4], bw[2];
#pragma unroll
      for (int fa = 0; fa < 4; fa++)
        af[fa] = *(const bf16x8*)&As[cur][(wr * 64 + fa * 16 + l15) * 72 + kk * 32 + lg * 8];
#pragma unroll
      for (int fb = 0; fb < 2; fb++)
        bw[fb] = *(const bf16x8*)&Bs[cur][(wc * 32 + fb * 16 + l15) * 72 + kk * 32 + lg * 8];
#pragma unroll
      for (int fa = 0; fa < 4; fa++)
#pragma unroll
        for (int fb = 0; fb < 2; fb++)
          acc[fa][fb] = __builtin_amdgcn_mfma_f32_16x16x32_bf16(af[fa], bw[fb], acc[fa][fb], 0, 0, 0);
    }
    if (t < II_ / 64 - 1) {
#pragma unroll
      for (int i = 0; i < 4; i++) *(uint4*)&As[cur ^ 1][(arow + 32 * i) * 72 + akg] = pa[i];
#pragma unroll
      for (int j = 0; j < 2; j++) *(uint4*)&Bs[cur ^ 1][(arow + 32 * j) * 72 + akg] = pb[j];
    }
    __syncthreads();
    cur ^= 1;
  }
#pragma unroll
  for (int fa = 0; fa < 4; fa++)
#pragma unroll
    for (int r = 0; r < 4; r++) {
      int prow = row0 + wr * 64 + fa * 16 + lg * 4 + r;
      if (prow < ne) {
        int p = pbase + prow;
        int ts = pairs_ts[p];
        float wgt = pairs_w[p];
#pragma unroll
        for (int fb = 0; fb < 2; fb++) {
          int col = col0 + wc * 32 + fb * 16 + l15;
          Pbuf[(size_t)ts * H_ + col] = wgt * acc[fa][fb][r];
        }
      }
    }
}

// ---------------- final: out = rmsnorm(resid + P0 + P1) ----------------
__global__ __launch_bounds__(256) void k_final(const float* __restrict__ resid, const float* __restrict__ Pbuf,
                                               const float* __restrict__ w, float* __restrict__ out) {
  int row = blockIdx.x;
  int tid = threadIdx.x;
  float4 a = ((const float4*)(resid + (size_t)row * H_))[tid];
  float4 p0 = ((const float4*)(Pbuf + (size_t)(2 * row) * H_))[tid];
  float4 p1 = ((const float4*)(Pbuf + (size_t)(2 * row + 1) * H_))[tid];
  float4 v;
  v.x = a.x + p0.x + p1.x; v.y = a.y + p0.y + p1.y; v.z = a.z + p0.z + p1.z; v.w = a.w + p0.w + p1.w;
  float ss = v.x * v.x + v.y * v.y + v.z * v.z + v.w * v.w;
#pragma unroll
  for (int off = 32; off; off >>= 1) ss += __shfl_xor(ss, off, 64);
  __shared__ float red[4];
  int lane = tid & 63, wid = tid >> 6;
  if (lane == 0) red[wid] = ss;
  __syncthreads();
  float tot = red[0] + red[1] + red[2] + red[3];
  float inv = rsqrtf(tot * (1.0f / H_) + 1e-5f);
  float4 wv = ((const float4*)w)[tid];
  float4 o;
  o.x = v.x * inv * wv.x; o.y = v.y * inv * wv.y; o.z = v.z * inv * wv.z; o.w = v.w * inv * wv.w;
  ((float4*)(out + (size_t)row * H_))[tid] = o;
}

extern "C" void kernel_launch(void* const* d_in, const int* in_sizes, int n_in,
                              void* d_out, int out_size, void* d_ws, size_t ws_size,
                              hipStream_t stream) {
  const float* x = (const float*)d_in[0];
  const int* pos = (const int*)d_in[1];
  const float* qkv_w = (const float*)d_in[2];
  const float* o_w = (const float*)d_in[3];
  const float* nin_w = (const float*)d_in[4];
  const float* npost_w = (const float*)d_in[5];
  const float* nnext_w = (const float*)d_in[6];
  const float* gate_w = (const float*)d_in[7];
  const float* w1 = (const float*)d_in[8];
  const float* w3 = (const float*)d_in[9];
  const float* w2 = (const float*)d_in[10];
  float* out = (float*)d_out;

  // ---- persistent region ----
  float* resid = (float*)d_ws;                       // T*H
  float* h2 = resid + (size_t)T_ * H_;               // T*H
  float* Pbuf = h2 + (size_t)T_ * H_;                // 2*T*H
  float* topw = Pbuf + (size_t)2 * T_ * H_;          // 2T
  float* pairsw = topw + T_ * 2;                     // 4096
  unsigned short* h2b = (unsigned short*)(pairsw + 4096);  // T*H
  unsigned short* G = h2b + (size_t)T_ * H_;         // 2*T*II
  int* topi = (int*)(G + (size_t)2 * T_ * II_);      // 2T
  int* ctrl = topi + T_ * 2;
  int* counts = ctrl;
  int* counts2 = ctrl + 8;
  int* offsets = ctrl + 16;
  int* pairs_ts = ctrl + 24;                         // 4096
  char* trans = (char*)(pairs_ts + 4096);
  trans = (char*)(((uintptr_t)trans + 255) & ~(uintptr_t)255);

  // ---- transient: attention phase ----
  unsigned short* Aq = (unsigned short*)trans;       // T*3072  (expanded rmsnorm(x))
  unsigned short* Bq = Aq + (size_t)T_ * 3072;       // 1536*3072 (expanded qkv_w)
  unsigned short* Bo = Bq + (size_t)1536 * 3072;     // 1024*3072 (expanded o_w)
  unsigned short* Ao = Bo + (size_t)1024 * 3072;     // T*3072 (expanded attn out)
  float* qkvb = (float*)(Ao + (size_t)T_ * 3072);    // T*1536
  float* ct = qkvb + (size_t)T_ * 1536;              // T*32
  float* st = ct + (size_t)T_ * 32;                  // T*32
  unsigned short* uu = (unsigned short*)(st + (size_t)T_ * 32);
  unsigned short* Qhi = uu;  uu += (size_t)HQ_ * T_ * D_;
  unsigned short* Qlo = uu;  uu += (size_t)HQ_ * T_ * D_;
  unsigned short* Khi = uu;  uu += (size_t)HK_ * T_ * D_;
  unsigned short* Klo = uu;  uu += (size_t)HK_ * T_ * D_;
  unsigned short* Vthi = uu; uu += (size_t)HK_ * D_ * T_;
  unsigned short* Vtlo = uu; uu += (size_t)HK_ * D_ * T_;

  // ---- transient: MoE phase (aliases attention transients; conv runs after router) ----
  unsigned short* W1b = (unsigned short*)trans;      // E*I*H
  unsigned short* W3b = W1b + (size_t)NE_ * II_ * H_;
  unsigned short* W2b = W3b + (size_t)NE_ * II_ * H_;

  const int WCNT8 = (NE_ * II_ * H_) / 8;

  hipMemsetAsync(ctrl, 0, 64, stream);  // counts + counts2
  k_rmsnorm_split<<<T_, 256, 0, stream>>>(x, nin_w, Aq);
  k_wsplit<<<2048, 256, 0, stream>>>(qkv_w, Bq, H_, 1536 * H_ / 8);
  k_wsplit<<<2048, 256, 0, stream>>>(o_w, Bo, HQ_ * D_, H_ * HQ_ * D_ / 8);
  k_hgemm<0><<<dim3(1536 / 64, T_ / 128), 256, 0, stream>>>(Aq, Bq, qkvb, nullptr, 1536, 3 * H_);
  k_rope_table<<<T_ * 32 / 256, 256, 0, stream>>>(pos, ct, st);
  k_rope_prep<<<T_, 256, 0, stream>>>(qkvb, ct, st, Qhi, Qlo, Khi, Klo);
  k_vtrans<<<dim3(T_ / 64, HK_), 256, 0, stream>>>(qkvb, Vthi, Vtlo);
  k_attn_mfma<<<dim3(512), 256, 0, stream>>>(Qhi, Qlo, Khi, Klo, Vthi, Vtlo, Ao);
  k_hgemm<1><<<dim3(H_ / 64, T_ / 128), 256, 0, stream>>>(Ao, Bo, resid, x, H_, 3 * HQ_ * D_);
  k_rmsnorm<<<T_, 256, 0, stream>>>(resid, npost_w, h2, h2b);
  k_router<<<T_ / 4, 256, 0, stream>>>(h2, gate_w, topi, topw, counts);
  k_scan<<<1, 64, 0, stream>>>(counts, offsets);
  k_build<<<T_ / 256, 256, 0, stream>>>(topi, topw, offsets, counts2, pairs_ts, pairsw);
  // weight pre-conversion (attention transients are dead now)
  k_conv<<<2048, 256, 0, stream>>>(w1, W1b, WCNT8);
  k_conv<<<2048, 256, 0, stream>>>(w3, W3b, WCNT8);
  k_conv<<<2048, 256, 0, stream>>>(w2, W2b, WCNT8);
  k_moe_up<<<dim3(II_ / 64, T_ / 128, NE_), 256, 0, stream>>>(h2b, W1b, W3b, pairs_ts, offsets, counts, G);
  k_moe_down<<<dim3(H_ / 64, T_ / 128, NE_), 256, 0, stream>>>(G, W2b, pairs_ts, pairsw, offsets, counts, Pbuf);
  k_final<<<T_, 256, 0, stream>>>(resid, Pbuf, nnext_w, out);
}

// Round 6
// 489.089 us; speedup vs baseline: 1.8415x; 1.1267x over previous
//
#include <hip/hip_runtime.h>
#include <hip/hip_bf16.h>
#include <math.h>

#define T_ 2048
#define H_ 1024
#define HQ_ 16
#define HK_ 4
#define D_ 64
#define NE_ 8
#define II_ 2048

typedef __attribute__((ext_vector_type(8))) short bf16x8;
typedef __attribute__((ext_vector_type(8))) unsigned short u16x8;
typedef __attribute__((ext_vector_type(4))) float f32x4;

// async global->LDS DMA: 16B per lane, dest = wave-uniform base + lane*16
#define GLOAD16(g, l)                                                                   \
  __builtin_amdgcn_global_load_lds((const __attribute__((address_space(1))) unsigned int*)(g), \
                                   (__attribute__((address_space(3))) unsigned int*)(l), 16, 0, 0)

__device__ __forceinline__ unsigned short f2bf(float f) {
  unsigned int u = __float_as_uint(f);
  return (unsigned short)((u + 0x7fffu + ((u >> 16) & 1u)) >> 16);
}
__device__ __forceinline__ float bf2f(unsigned short h) {
  return __uint_as_float((unsigned int)h << 16);
}

// ---------------- rmsnorm (fp32 in, fp32 out + optional bf16 out) ----------------
__global__ __launch_bounds__(256) void k_rmsnorm(const float* __restrict__ x, const float* __restrict__ w,
                                                 float* __restrict__ outf, unsigned short* __restrict__ outb) {
  int row = blockIdx.x;
  int tid = threadIdx.x;
  float4 v = ((const float4*)(x + (size_t)row * H_))[tid];
  float ss = v.x * v.x + v.y * v.y + v.z * v.z + v.w * v.w;
#pragma unroll
  for (int off = 32; off; off >>= 1) ss += __shfl_xor(ss, off, 64);
  __shared__ float red[4];
  int lane = tid & 63, wid = tid >> 6;
  if (lane == 0) red[wid] = ss;
  __syncthreads();
  float tot = red[0] + red[1] + red[2] + red[3];
  float inv = rsqrtf(tot * (1.0f / H_) + 1e-5f);
  float4 wv = ((const float4*)w)[tid];
  float4 o;
  o.x = v.x * inv * wv.x; o.y = v.y * inv * wv.y; o.z = v.z * inv * wv.z; o.w = v.w * inv * wv.w;
  ((float4*)(outf + (size_t)row * H_))[tid] = o;
  if (outb) {
    ushort4 b; b.x = f2bf(o.x); b.y = f2bf(o.y); b.z = f2bf(o.z); b.w = f2bf(o.w);
    ((ushort4*)(outb + (size_t)row * H_))[tid] = b;
  }
}

// ---------------- rmsnorm writing expanded bf16x3 A' = [hi|hi|lo] along K'=3H ----------------
__global__ __launch_bounds__(256) void k_rmsnorm_split(const float* __restrict__ x, const float* __restrict__ w,
                                                       unsigned short* __restrict__ Aq) {
  int row = blockIdx.x;
  int tid = threadIdx.x;
  float4 v = ((const float4*)(x + (size_t)row * H_))[tid];
  float ss = v.x * v.x + v.y * v.y + v.z * v.z + v.w * v.w;
#pragma unroll
  for (int off = 32; off; off >>= 1) ss += __shfl_xor(ss, off, 64);
  __shared__ float red[4];
  int lane = tid & 63, wid = tid >> 6;
  if (lane == 0) red[wid] = ss;
  __syncthreads();
  float tot = red[0] + red[1] + red[2] + red[3];
  float inv = rsqrtf(tot * (1.0f / H_) + 1e-5f);
  float4 wv = ((const float4*)w)[tid];
  float4 o;
  o.x = v.x * inv * wv.x; o.y = v.y * inv * wv.y; o.z = v.z * inv * wv.z; o.w = v.w * inv * wv.w;
  ushort4 hi, lo;
  hi.x = f2bf(o.x); hi.y = f2bf(o.y); hi.z = f2bf(o.z); hi.w = f2bf(o.w);
  lo.x = f2bf(o.x - bf2f(hi.x)); lo.y = f2bf(o.y - bf2f(hi.y));
  lo.z = f2bf(o.z - bf2f(hi.z)); lo.w = f2bf(o.w - bf2f(hi.w));
  size_t base = (size_t)row * (3 * H_) + tid * 4;
  *(ushort4*)(Aq + base) = hi;
  *(ushort4*)(Aq + base + H_) = hi;
  *(ushort4*)(Aq + base + 2 * H_) = lo;
}

// ---------------- weight split: W[N][K] fp32 -> W'[N][3K] bf16 = [hi|lo|hi] ----------------
__global__ __launch_bounds__(256) void k_wsplit(const float* __restrict__ in, unsigned short* __restrict__ out,
                                                int K, int n8total) {
  int stride = gridDim.x * 256;
  int kc8 = K >> 3;
  for (int i = blockIdx.x * 256 + threadIdx.x; i < n8total; i += stride) {
    int n = i / kc8, kc = (i - n * kc8) * 8;
    const float4* p = (const float4*)(in + (size_t)n * K + kc);
    float4 a = p[0], b = p[1];
    u16x8 hi, lo;
    hi[0] = f2bf(a.x); hi[1] = f2bf(a.y); hi[2] = f2bf(a.z); hi[3] = f2bf(a.w);
    hi[4] = f2bf(b.x); hi[5] = f2bf(b.y); hi[6] = f2bf(b.z); hi[7] = f2bf(b.w);
    lo[0] = f2bf(a.x - bf2f(hi[0])); lo[1] = f2bf(a.y - bf2f(hi[1]));
    lo[2] = f2bf(a.z - bf2f(hi[2])); lo[3] = f2bf(a.w - bf2f(hi[3]));
    lo[4] = f2bf(b.x - bf2f(hi[4])); lo[5] = f2bf(b.y - bf2f(hi[5]));
    lo[6] = f2bf(b.z - bf2f(hi[6])); lo[7] = f2bf(b.w - bf2f(hi[7]));
    size_t ob = (size_t)n * 3 * K + kc;
    *(u16x8*)(out + ob) = hi;
    *(u16x8*)(out + ob + K) = lo;
    *(u16x8*)(out + ob + 2 * K) = hi;
  }
}

// ---------------- bf16 GEMM (expanded-K bf16x3), m97-style gload_lds + dbuf ----------------
// 128x64 tile, BK=32, linear LDS [row][32], one barrier per K-step
template <int ADD>
__global__ __launch_bounds__(256) void k_hgemm(const unsigned short* __restrict__ A, const unsigned short* __restrict__ B,
                                               float* __restrict__ C, const float* __restrict__ addsrc,
                                               int N, int K3) {
  int m0 = blockIdx.y * 128, n0 = blockIdx.x * 64;
  __shared__ unsigned short As[2][128 * 32];
  __shared__ unsigned short Bs[2][64 * 32];
  int tid = threadIdx.x, lane = tid & 63, w = tid >> 6;
  int wr = w >> 1, wc = w & 1;
  int l15 = lane & 15, lg = lane >> 4;
  int srow = lane >> 2, schunk = lane & 3;  // staging: 16 rows/instr, 16B chunk in 64B row

  const unsigned short* ga0 = A + (size_t)(m0 + w * 32 + srow) * K3 + schunk * 8;
  const unsigned short* ga1 = A + (size_t)(m0 + w * 32 + 16 + srow) * K3 + schunk * 8;
  const unsigned short* gb = B + (size_t)(n0 + w * 16 + srow) * K3 + schunk * 8;

  f32x4 acc[4][2];
  f32x4 z = {0.f, 0.f, 0.f, 0.f};
#pragma unroll
  for (int a = 0; a < 4; a++)
#pragma unroll
    for (int b = 0; b < 2; b++) acc[a][b] = z;

  GLOAD16(ga0, &As[0][(w * 32) * 32]);
  GLOAD16(ga1, &As[0][(w * 32 + 16) * 32]);
  GLOAD16(gb, &Bs[0][(w * 16) * 32]);
  __syncthreads();

  int nt = K3 / 32;
  for (int t = 0; t < nt; ++t) {
    int cur = t & 1;
    if (t + 1 < nt) {
      int ko = (t + 1) * 32;
      GLOAD16(ga0 + ko, &As[cur ^ 1][(w * 32) * 32]);
      GLOAD16(ga1 + ko, &As[cur ^ 1][(w * 32 + 16) * 32]);
      GLOAD16(gb + ko, &Bs[cur ^ 1][(w * 16) * 32]);
    }
    bf16x8 af[4], bw2[2];
#pragma unroll
    for (int fa = 0; fa < 4; fa++)
      af[fa] = *(const bf16x8*)&As[cur][(wr * 64 + fa * 16 + l15) * 32 + lg * 8];
#pragma unroll
    for (int fb = 0; fb < 2; fb++)
      bw2[fb] = *(const bf16x8*)&Bs[cur][(wc * 32 + fb * 16 + l15) * 32 + lg * 8];
#pragma unroll
    for (int fa = 0; fa < 4; fa++)
#pragma unroll
      for (int fb = 0; fb < 2; fb++)
        acc[fa][fb] = __builtin_amdgcn_mfma_f32_16x16x32_bf16(af[fa], bw2[fb], acc[fa][fb], 0, 0, 0);
    __syncthreads();
  }
#pragma unroll
  for (int fa = 0; fa < 4; fa++)
#pragma unroll
    for (int r = 0; r < 4; r++) {
      int row = m0 + wr * 64 + fa * 16 + lg * 4 + r;
#pragma unroll
      for (int fb = 0; fb < 2; fb++) {
        int col = n0 + wc * 32 + fb * 16 + l15;
        float v = acc[fa][fb][r];
        if (ADD) v += addsrc[(size_t)row * N + col];
        C[(size_t)row * N + col] = v;
      }
    }
}

// ---------------- RoPE cos/sin table (matches np float32 angle bits) ----------------
__global__ __launch_bounds__(256) void k_rope_table(const int* __restrict__ pos, float* __restrict__ ct,
                                                    float* __restrict__ st) {
  int idx = blockIdx.x * 256 + threadIdx.x;  // T*32
  int t = idx >> 5, i = idx & 31;
  float p = (float)pow(10000.0, (double)i / 32.0);
  float freq = 1.0f / p;
  float ang = (float)pos[t] * freq;
  ct[idx] = cosf(ang);
  st[idx] = sinf(ang);
}

// ---------------- RoPE apply + bf16 hi/lo split ----------------
__global__ __launch_bounds__(256) void k_rope_prep(const float* __restrict__ qkv, const float* __restrict__ ct,
                                                   const float* __restrict__ st, unsigned short* __restrict__ Qhi,
                                                   unsigned short* __restrict__ Qlo, unsigned short* __restrict__ Khi,
                                                   unsigned short* __restrict__ Klo) {
  int t = blockIdx.x, tid = threadIdx.x;
  const float* row = qkv + (size_t)t * 1536;
#pragma unroll 2
  for (int it = tid; it < 512; it += 256) {
    int h = it >> 5, i = it & 31;
    float c = ct[t * 32 + i], s = st[t * 32 + i];
    float x1 = row[h * 64 + i], x2 = row[h * 64 + i + 32];
    float a = (x1 * c - x2 * s) * 0.125f;
    float b = (x2 * c + x1 * s) * 0.125f;
    size_t base = ((size_t)h * T_ + t) * 64 + i;
    unsigned short ah = f2bf(a), bh = f2bf(b);
    Qhi[base] = ah; Qhi[base + 32] = bh;
    Qlo[base] = f2bf(a - bf2f(ah));
    Qlo[base + 32] = f2bf(b - bf2f(bh));
  }
  if (tid < 128) {
    int h = tid >> 5, i = tid & 31;
    float c = ct[t * 32 + i], s = st[t * 32 + i];
    float x1 = row[1024 + h * 64 + i], x2 = row[1024 + h * 64 + i + 32];
    float a = x1 * c - x2 * s;
    float b = x2 * c + x1 * s;
    size_t base = ((size_t)h * T_ + t) * 64 + i;
    unsigned short ah = f2bf(a), bh = f2bf(b);
    Khi[base] = ah; Khi[base + 32] = bh;
    Klo[base] = f2bf(a - bf2f(ah));
    Klo[base + 32] = f2bf(b - bf2f(bh));
  }
}

// ---------------- V transpose + split: Vthi/Vtlo [kvh][d][t] ----------------
__global__ __launch_bounds__(256) void k_vtrans(const float* __restrict__ qkv, unsigned short* __restrict__ Vthi,
                                                unsigned short* __restrict__ Vtlo) {
  int t0 = blockIdx.x * 64, h = blockIdx.y;
  __shared__ float tile[64][65];
  int tid = threadIdx.x;
  int c = tid & 63, w = tid >> 6;
  for (int r = w; r < 64; r += 4)
    tile[r][c] = qkv[(size_t)(t0 + r) * 1536 + 1280 + h * 64 + c];
  __syncthreads();
  for (int d = w; d < 64; d += 4) {
    float v = tile[c][d];
    unsigned short hi = f2bf(v);
    size_t idx = ((size_t)h * 64 + d) * T_ + t0 + c;
    Vthi[idx] = hi;
    Vtlo[idx] = f2bf(v - bf2f(hi));
  }
}

// ---------------- flash attention, bf16x3 split MFMA; epilogue writes expanded A'o ----------------
__global__ __launch_bounds__(256) void k_attn_mfma(const unsigned short* __restrict__ Qhi,
                                                   const unsigned short* __restrict__ Qlo,
                                                   const unsigned short* __restrict__ Khi,
                                                   const unsigned short* __restrict__ Klo,
                                                   const unsigned short* __restrict__ Vthi,
                                                   const unsigned short* __restrict__ Vtlo,
                                                   unsigned short* __restrict__ Ao) {
  int bid = blockIdx.x;
  int kk = bid >> 4;
  int head = bid & 15;
  int qidx = (kk < 16) ? (31 - kk) : (kk - 16);
  int qb = qidx * 64;
  int kvh = head >> 2;
  int tid = threadIdx.x, lane = tid & 63, w = tid >> 6;
  int l15 = lane & 15, lg = lane >> 4;

  __shared__ unsigned short KsH[64 * 72], KsL[64 * 72];
  __shared__ unsigned short VsH[64 * 72], VsL[64 * 72];
  __shared__ unsigned short PsH[64 * 72], PsL[64 * 72];

  bf16x8 qh[2], ql[2];
  {
    size_t qbase = ((size_t)head * T_ + qb + w * 16 + l15) * 64 + lg * 8;
    qh[0] = *(const bf16x8*)(Qhi + qbase);
    qh[1] = *(const bf16x8*)(Qhi + qbase + 32);
    ql[0] = *(const bf16x8*)(Qlo + qbase);
    ql[1] = *(const bf16x8*)(Qlo + qbase + 32);
  }
  f32x4 z = {0.f, 0.f, 0.f, 0.f};
  f32x4 Oa[4];
  float mrow[4], lrow[4];
#pragma unroll
  for (int r = 0; r < 4; r++) { mrow[r] = -1e30f; lrow[r] = 0.f; }
#pragma unroll
  for (int dg = 0; dg < 4; dg++) Oa[dg] = z;

  for (int jb = 0; jb <= qb; jb += 64) {
    __syncthreads();
    for (int c = tid; c < 512; c += 256) {
      int r = c >> 3, g = (c & 7) * 8;
      size_t kgl = ((size_t)kvh * T_ + jb + r) * 64 + g;
      size_t vgl = ((size_t)kvh * 64 + r) * T_ + jb + g;
      *(uint4*)&KsH[r * 72 + g] = *(const uint4*)(Khi + kgl);
      *(uint4*)&KsL[r * 72 + g] = *(const uint4*)(Klo + kgl);
      *(uint4*)&VsH[r * 72 + g] = *(const uint4*)(Vthi + vgl);
      *(uint4*)&VsL[r * 72 + g] = *(const uint4*)(Vtlo + vgl);
    }
    __syncthreads();

    f32x4 sc[4];
    sc[0] = z; sc[1] = z; sc[2] = z; sc[3] = z;
#pragma unroll
    for (int kg = 0; kg < 4; kg++) {
      int ba = (kg * 16 + l15) * 72 + lg * 8;
      bf16x8 bh0 = *(const bf16x8*)&KsH[ba];
      bf16x8 bh1 = *(const bf16x8*)&KsH[ba + 32];
      bf16x8 bl0 = *(const bf16x8*)&KsL[ba];
      bf16x8 bl1 = *(const bf16x8*)&KsL[ba + 32];
      sc[kg] = __builtin_amdgcn_mfma_f32_16x16x32_bf16(qh[0], bh0, sc[kg], 0, 0, 0);
      sc[kg] = __builtin_amdgcn_mfma_f32_16x16x32_bf16(qh[1], bh1, sc[kg], 0, 0, 0);
      sc[kg] = __builtin_amdgcn_mfma_f32_16x16x32_bf16(qh[0], bl0, sc[kg], 0, 0, 0);
      sc[kg] = __builtin_amdgcn_mfma_f32_16x16x32_bf16(qh[1], bl1, sc[kg], 0, 0, 0);
      sc[kg] = __builtin_amdgcn_mfma_f32_16x16x32_bf16(ql[0], bh0, sc[kg], 0, 0, 0);
      sc[kg] = __builtin_amdgcn_mfma_f32_16x16x32_bf16(ql[1], bh1, sc[kg], 0, 0, 0);
    }
    if (jb == qb) {
      int rb = w * 16 + lg * 4;
#pragma unroll
      for (int kg = 0; kg < 4; kg++) {
        int col = kg * 16 + l15;
#pragma unroll
        for (int r = 0; r < 4; r++)
          if (col > rb + r) sc[kg][r] = -1e30f;
      }
    }
#pragma unroll
    for (int r = 0; r < 4; r++) {
      float mt = fmaxf(fmaxf(sc[0][r], sc[1][r]), fmaxf(sc[2][r], sc[3][r]));
      mt = fmaxf(mt, __shfl_xor(mt, 1, 64));
      mt = fmaxf(mt, __shfl_xor(mt, 2, 64));
      mt = fmaxf(mt, __shfl_xor(mt, 4, 64));
      mt = fmaxf(mt, __shfl_xor(mt, 8, 64));
      float mnew = fmaxf(mrow[r], mt);
      float corr = __expf(mrow[r] - mnew);
      mrow[r] = mnew;
      float s = 0.f;
#pragma unroll
      for (int kg = 0; kg < 4; kg++) {
        float p = __expf(sc[kg][r] - mnew);
        sc[kg][r] = p;
        s += p;
      }
      s += __shfl_xor(s, 1, 64);
      s += __shfl_xor(s, 2, 64);
      s += __shfl_xor(s, 4, 64);
      s += __shfl_xor(s, 8, 64);
      lrow[r] = lrow[r] * corr + s;
      // per-ROW rescale (Oa[dg] components are 4 different rows)
#pragma unroll
      for (int dg = 0; dg < 4; dg++) Oa[dg][r] *= corr;
    }
    {
      int rb = w * 16 + lg * 4;
#pragma unroll
      for (int kg = 0; kg < 4; kg++) {
        int col = kg * 16 + l15;
#pragma unroll
        for (int r = 0; r < 4; r++) {
          float p = sc[kg][r];
          unsigned short ph = f2bf(p);
          PsH[(rb + r) * 72 + col] = ph;
          PsL[(rb + r) * 72 + col] = f2bf(p - bf2f(ph));
        }
      }
    }
    {
      int ab = (w * 16 + l15) * 72 + lg * 8;
      bf16x8 ph0 = *(const bf16x8*)&PsH[ab];
      bf16x8 ph1 = *(const bf16x8*)&PsH[ab + 32];
      bf16x8 pl0 = *(const bf16x8*)&PsL[ab];
      bf16x8 pl1 = *(const bf16x8*)&PsL[ab + 32];
#pragma unroll
      for (int dg = 0; dg < 4; dg++) {
        int vb = (dg * 16 + l15) * 72 + lg * 8;
        bf16x8 vh0 = *(const bf16x8*)&VsH[vb];
        bf16x8 vh1 = *(const bf16x8*)&VsH[vb + 32];
        bf16x8 vl0 = *(const bf16x8*)&VsL[vb];
        bf16x8 vl1 = *(const bf16x8*)&VsL[vb + 32];
        Oa[dg] = __builtin_amdgcn_mfma_f32_16x16x32_bf16(ph0, vh0, Oa[dg], 0, 0, 0);
        Oa[dg] = __builtin_amdgcn_mfma_f32_16x16x32_bf16(ph1, vh1, Oa[dg], 0, 0, 0);
        Oa[dg] = __builtin_amdgcn_mfma_f32_16x16x32_bf16(ph0, vl0, Oa[dg], 0, 0, 0);
        Oa[dg] = __builtin_amdgcn_mfma_f32_16x16x32_bf16(ph1, vl1, Oa[dg], 0, 0, 0);
        Oa[dg] = __builtin_amdgcn_mfma_f32_16x16x32_bf16(pl0, vh0, Oa[dg], 0, 0, 0);
        Oa[dg] = __builtin_amdgcn_mfma_f32_16x16x32_bf16(pl1, vh1, Oa[dg], 0, 0, 0);
      }
    }
  }
#pragma unroll
  for (int r = 0; r < 4; r++) {
    float inv = 1.0f / lrow[r];
    size_t rb2 = (size_t)(qb + w * 16 + lg * 4 + r) * 3072 + head * 64;
#pragma unroll
    for (int dg = 0; dg < 4; dg++) {
      float v = Oa[dg][r] * inv;
      unsigned short hi = f2bf(v);
      unsigned short lo = f2bf(v - bf2f(hi));
      Ao[rb2 + dg * 16 + l15] = hi;
      Ao[rb2 + 1024 + dg * 16 + l15] = hi;
      Ao[rb2 + 2048 + dg * 16 + l15] = lo;
    }
  }
}

// ---------------- router ----------------
__global__ __launch_bounds__(256) void k_router(const float* __restrict__ h2, const float* __restrict__ gw,
                                                int* __restrict__ topi, float* __restrict__ topw,
                                                int* __restrict__ counts) {
  int wid = threadIdx.x >> 6, lane = threadIdx.x & 63;
  int t = blockIdx.x * 4 + wid;
  const float* hr = h2 + (size_t)t * H_;
  float hv[16];
#pragma unroll
  for (int i = 0; i < 16; i++) hv[i] = hr[lane + 64 * i];
  float le[8];
#pragma unroll
  for (int e = 0; e < 8; e++) {
    const float* g = gw + (size_t)e * H_;
    float acc = 0.f;
#pragma unroll
    for (int i = 0; i < 16; i++) acc += hv[i] * g[lane + 64 * i];
#pragma unroll
    for (int off = 32; off; off >>= 1) acc += __shfl_xor(acc, off, 64);
    le[e] = acc;
  }
  if (lane == 0) {
    int i0 = 0;
#pragma unroll
    for (int e = 1; e < 8; e++)
      if (le[e] > le[i0]) i0 = e;
    int i1 = (i0 == 0) ? 1 : 0;
#pragma unroll
    for (int e = 0; e < 8; e++) {
      if (e == i0) continue;
      if (le[e] > le[i1]) i1 = e;
    }
    float w1r = expf(le[i1] - le[i0]);
    float denom = 1.0f + w1r;
    topi[t * 2 + 0] = i0;
    topi[t * 2 + 1] = i1;
    topw[t * 2 + 0] = 1.0f / denom;
    topw[t * 2 + 1] = w1r / denom;
    atomicAdd(&counts[i0], 1);
    atomicAdd(&counts[i1], 1);
  }
}

__global__ void k_scan(const int* __restrict__ counts, int* __restrict__ offsets) {
  if (threadIdx.x == 0 && blockIdx.x == 0) {
    int off = 0;
    for (int e = 0; e < NE_; e++) { offsets[e] = off; off += counts[e]; }
  }
}

__global__ __launch_bounds__(256) void k_build(const int* __restrict__ topi, const float* __restrict__ topw,
                                               const int* __restrict__ offsets, int* __restrict__ counts2,
                                               int* __restrict__ pairs_ts, float* __restrict__ pairs_w) {
  int t = blockIdx.x * 256 + threadIdx.x;
#pragma unroll
  for (int s = 0; s < 2; s++) {
    int e = topi[t * 2 + s];
    int slot = atomicAdd(&counts2[e], 1);
    int p = offsets[e] + slot;
    pairs_ts[p] = t * 2 + s;
    pairs_w[p] = topw[t * 2 + s];
  }
}

// ---------------- fp32 -> bf16 bulk convert ----------------
__global__ __launch_bounds__(256) void k_conv(const float* __restrict__ in, unsigned short* __restrict__ out, int n8) {
  int stride = gridDim.x * 256;
  for (int i = blockIdx.x * 256 + threadIdx.x; i < n8; i += stride) {
    const float4* p = (const float4*)in + (size_t)i * 2;
    float4 a = p[0], b = p[1];
    u16x8 t;
    t[0] = f2bf(a.x); t[1] = f2bf(a.y); t[2] = f2bf(a.z); t[3] = f2bf(a.w);
    t[4] = f2bf(b.x); t[5] = f2bf(b.y); t[6] = f2bf(b.z); t[7] = f2bf(b.w);
    *((u16x8*)out + i) = t;
  }
}

// ---------------- MoE up: 128x64 tile, BK=32, gload_lds dbuf, silu epilogue ----------------
__global__ __launch_bounds__(256) void k_moe_up(const unsigned short* __restrict__ h2b, const unsigned short* __restrict__ W1b,
                                                const unsigned short* __restrict__ W3b, const int* __restrict__ pairs_ts,
                                                const int* __restrict__ offsets, const int* __restrict__ counts,
                                                unsigned short* __restrict__ G) {
  int e = blockIdx.z;
  int ne = counts[e];
  int row0 = blockIdx.y * 128;
  if (row0 >= ne) return;
  int col0 = blockIdx.x * 64;
  int pbase = offsets[e];
  __shared__ unsigned short As[2][128 * 32];
  __shared__ unsigned short B1s[2][64 * 32];
  __shared__ unsigned short B2s[2][64 * 32];
  int tid = threadIdx.x, lane = tid & 63, w = tid >> 6;
  int wr = w >> 1, wc = w & 1;
  int l15 = lane & 15, lg = lane >> 4;
  int srow = lane >> 2, schunk = lane & 3;

  int gr0 = row0 + w * 32 + srow, gr1 = gr0 + 16;
  int tok0 = (gr0 < ne) ? (pairs_ts[pbase + gr0] >> 1) : 0;
  int tok1 = (gr1 < ne) ? (pairs_ts[pbase + gr1] >> 1) : 0;
  const unsigned short* ga0 = h2b + (size_t)tok0 * H_ + schunk * 8;
  const unsigned short* ga1 = h2b + (size_t)tok1 * H_ + schunk * 8;
  const unsigned short* gb1 = W1b + ((size_t)e * II_ + col0 + w * 16 + srow) * H_ + schunk * 8;
  const unsigned short* gb3 = W3b + ((size_t)e * II_ + col0 + w * 16 + srow) * H_ + schunk * 8;

  f32x4 acc1[4][2], acc2[4][2];
  f32x4 z = {0.f, 0.f, 0.f, 0.f};
#pragma unroll
  for (int a = 0; a < 4; a++)
#pragma unroll
    for (int b = 0; b < 2; b++) { acc1[a][b] = z; acc2[a][b] = z; }

  GLOAD16(ga0, &As[0][(w * 32) * 32]);
  GLOAD16(ga1, &As[0][(w * 32 + 16) * 32]);
  GLOAD16(gb1, &B1s[0][(w * 16) * 32]);
  GLOAD16(gb3, &B2s[0][(w * 16) * 32]);
  __syncthreads();

  for (int t = 0; t < H_ / 32; ++t) {
    int cur = t & 1;
    if (t + 1 < H_ / 32) {
      int ko = (t + 1) * 32;
      GLOAD16(ga0 + ko, &As[cur ^ 1][(w * 32) * 32]);
      GLOAD16(ga1 + ko, &As[cur ^ 1][(w * 32 + 16) * 32]);
      GLOAD16(gb1 + ko, &B1s[cur ^ 1][(w * 16) * 32]);
      GLOAD16(gb3 + ko, &B2s[cur ^ 1][(w * 16) * 32]);
    }
    bf16x8 af[4], b1f[2], b2f[2];
#pragma unroll
    for (int fa = 0; fa < 4; fa++)
      af[fa] = *(const bf16x8*)&As[cur][(wr * 64 + fa * 16 + l15) * 32 + lg * 8];
#pragma unroll
    for (int fb = 0; fb < 2; fb++) {
      b1f[fb] = *(const bf16x8*)&B1s[cur][(wc * 32 + fb * 16 + l15) * 32 + lg * 8];
      b2f[fb] = *(const bf16x8*)&B2s[cur][(wc * 32 + fb * 16 + l15) * 32 + lg * 8];
    }
#pragma unroll
    for (int fa = 0; fa < 4; fa++)
#pragma unroll
      for (int fb = 0; fb < 2; fb++) {
        acc1[fa][fb] = __builtin_amdgcn_mfma_f32_16x16x32_bf16(af[fa], b1f[fb], acc1[fa][fb], 0, 0, 0);
        acc2[fa][fb] = __builtin_amdgcn_mfma_f32_16x16x32_bf16(af[fa], b2f[fb], acc2[fa][fb], 0, 0, 0);
      }
    __syncthreads();
  }
#pragma unroll
  for (int fa = 0; fa < 4; fa++)
#pragma unroll
    for (int r = 0; r < 4; r++) {
      int prow = row0 + wr * 64 + fa * 16 + lg * 4 + r;
      if (prow < ne) {
#pragma unroll
        for (int fb = 0; fb < 2; fb++) {
          int icol = col0 + wc * 32 + fb * 16 + l15;
          float h1 = acc1[fa][fb][r], h3 = acc2[fa][fb][r];
          float g = h1 / (1.0f + __expf(-h1)) * h3;
          G[(size_t)(pbase + prow) * II_ + icol] = f2bf(g);
        }
      }
    }
}

// ---------------- MoE down: 128x64 tile, BK=32, gload_lds dbuf, weighted store ----------------
__global__ __launch_bounds__(256) void k_moe_down(const unsigned short* __restrict__ G, const unsigned short* __restrict__ W2b,
                                                  const int* __restrict__ pairs_ts, const float* __restrict__ pairs_w,
                                                  const int* __restrict__ offsets, const int* __restrict__ counts,
                                                  float* __restrict__ Pbuf) {
  int e = blockIdx.z;
  int ne = counts[e];
  int row0 = blockIdx.y * 128;
  if (row0 >= ne) return;
  int col0 = blockIdx.x * 64;
  int pbase = offsets[e];
  __shared__ unsigned short As[2][128 * 32];
  __shared__ unsigned short Bs[2][64 * 32];
  int tid = threadIdx.x, lane = tid & 63, w = tid >> 6;
  int wr = w >> 1, wc = w & 1;
  int l15 = lane & 15, lg = lane >> 4;
  int srow = lane >> 2, schunk = lane & 3;

  int gr0 = row0 + w * 32 + srow, gr1 = gr0 + 16;
  int p0 = pbase + ((gr0 < ne) ? gr0 : 0);
  int p1 = pbase + ((gr1 < ne) ? gr1 : 0);
  const unsigned short* ga0 = G + (size_t)p0 * II_ + schunk * 8;
  const unsigned short* ga1 = G + (size_t)p1 * II_ + schunk * 8;
  const unsigned short* gb = W2b + ((size_t)e * H_ + col0 + w * 16 + srow) * II_ + schunk * 8;

  f32x4 acc[4][2];
  f32x4 z = {0.f, 0.f, 0.f, 0.f};
#pragma unroll
  for (int a = 0; a < 4; a++)
#pragma unroll
    for (int b = 0; b < 2; b++) acc[a][b] = z;

  GLOAD16(ga0, &As[0][(w * 32) * 32]);
  GLOAD16(ga1, &As[0][(w * 32 + 16) * 32]);
  GLOAD16(gb, &Bs[0][(w * 16) * 32]);
  __syncthreads();

  for (int t = 0; t < II_ / 32; ++t) {
    int cur = t & 1;
    if (t + 1 < II_ / 32) {
      int ko = (t + 1) * 32;
      GLOAD16(ga0 + ko, &As[cur ^ 1][(w * 32) * 32]);
      GLOAD16(ga1 + ko, &As[cur ^ 1][(w * 32 + 16) * 32]);
      GLOAD16(gb + ko, &Bs[cur ^ 1][(w * 16) * 32]);
    }
    bf16x8 af[4], bw2[2];
#pragma unroll
    for (int fa = 0; fa < 4; fa++)
      af[fa] = *(const bf16x8*)&As[cur][(wr * 64 + fa * 16 + l15) * 32 + lg * 8];
#pragma unroll
    for (int fb = 0; fb < 2; fb++)
      bw2[fb] = *(const bf16x8*)&Bs[cur][(wc * 32 + fb * 16 + l15) * 32 + lg * 8];
#pragma unroll
    for (int fa = 0; fa < 4; fa++)
#pragma unroll
      for (int fb = 0; fb < 2; fb++)
        acc[fa][fb] = __builtin_amdgcn_mfma_f32_16x16x32_bf16(af[fa], bw2[fb], acc[fa][fb], 0, 0, 0);
    __syncthreads();
  }
#pragma unroll
  for (int fa = 0; fa < 4; fa++)
#pragma unroll
    for (int r = 0; r < 4; r++) {
      int prow = row0 + wr * 64 + fa * 16 + lg * 4 + r;
      if (prow < ne) {
        int p = pbase + prow;
        int ts = pairs_ts[p];
        float wgt = pairs_w[p];
#pragma unroll
        for (int fb = 0; fb < 2; fb++) {
          int col = col0 + wc * 32 + fb * 16 + l15;
          Pbuf[(size_t)ts * H_ + col] = wgt * acc[fa][fb][r];
        }
      }
    }
}

// ---------------- final: out = rmsnorm(resid + P0 + P1) ----------------
__global__ __launch_bounds__(256) void k_final(const float* __restrict__ resid, const float* __restrict__ Pbuf,
                                               const float* __restrict__ w, float* __restrict__ out) {
  int row = blockIdx.x;
  int tid = threadIdx.x;
  float4 a = ((const float4*)(resid + (size_t)row * H_))[tid];
  float4 p0 = ((const float4*)(Pbuf + (size_t)(2 * row) * H_))[tid];
  float4 p1 = ((const float4*)(Pbuf + (size_t)(2 * row + 1) * H_))[tid];
  float4 v;
  v.x = a.x + p0.x + p1.x; v.y = a.y + p0.y + p1.y; v.z = a.z + p0.z + p1.z; v.w = a.w + p0.w + p1.w;
  float ss = v.x * v.x + v.y * v.y + v.z * v.z + v.w * v.w;
#pragma unroll
  for (int off = 32; off; off >>= 1) ss += __shfl_xor(ss, off, 64);
  __shared__ float red[4];
  int lane = tid & 63, wid = tid >> 6;
  if (lane == 0) red[wid] = ss;
  __syncthreads();
  float tot = red[0] + red[1] + red[2] + red[3];
  float inv = rsqrtf(tot * (1.0f / H_) + 1e-5f);
  float4 wv = ((const float4*)w)[tid];
  float4 o;
  o.x = v.x * inv * wv.x; o.y = v.y * inv * wv.y; o.z = v.z * inv * wv.z; o.w = v.w * inv * wv.w;
  ((float4*)(out + (size_t)row * H_))[tid] = o;
}

extern "C" void kernel_launch(void* const* d_in, const int* in_sizes, int n_in,
                              void* d_out, int out_size, void* d_ws, size_t ws_size,
                              hipStream_t stream) {
  const float* x = (const float*)d_in[0];
  const int* pos = (const int*)d_in[1];
  const float* qkv_w = (const float*)d_in[2];
  const float* o_w = (const float*)d_in[3];
  const float* nin_w = (const float*)d_in[4];
  const float* npost_w = (const float*)d_in[5];
  const float* nnext_w = (const float*)d_in[6];
  const float* gate_w = (const float*)d_in[7];
  const float* w1 = (const float*)d_in[8];
  const float* w3 = (const float*)d_in[9];
  const float* w2 = (const float*)d_in[10];
  float* out = (float*)d_out;

  // ---- persistent region ----
  float* resid = (float*)d_ws;                       // T*H
  float* h2 = resid + (size_t)T_ * H_;               // T*H
  float* Pbuf = h2 + (size_t)T_ * H_;                // 2*T*H
  float* topw = Pbuf + (size_t)2 * T_ * H_;          // 2T
  float* pairsw = topw + T_ * 2;                     // 4096
  unsigned short* h2b = (unsigned short*)(pairsw + 4096);  // T*H
  unsigned short* G = h2b + (size_t)T_ * H_;         // 2*T*II
  int* topi = (int*)(G + (size_t)2 * T_ * II_);      // 2T
  int* ctrl = topi + T_ * 2;
  int* counts = ctrl;
  int* counts2 = ctrl + 8;
  int* offsets = ctrl + 16;
  int* pairs_ts = ctrl + 24;                         // 4096
  char* trans = (char*)(pairs_ts + 4096);
  trans = (char*)(((uintptr_t)trans + 255) & ~(uintptr_t)255);

  // ---- transient: attention phase ----
  unsigned short* Aq = (unsigned short*)trans;       // T*3072  (expanded rmsnorm(x))
  unsigned short* Bq = Aq + (size_t)T_ * 3072;       // 1536*3072 (expanded qkv_w)
  unsigned short* Bo = Bq + (size_t)1536 * 3072;     // 1024*3072 (expanded o_w)
  unsigned short* Ao = Bo + (size_t)1024 * 3072;     // T*3072 (expanded attn out)
  float* qkvb = (float*)(Ao + (size_t)T_ * 3072);    // T*1536
  float* ct = qkvb + (size_t)T_ * 1536;              // T*32
  float* st = ct + (size_t)T_ * 32;                  // T*32
  unsigned short* uu = (unsigned short*)(st + (size_t)T_ * 32);
  unsigned short* Qhi = uu;  uu += (size_t)HQ_ * T_ * D_;
  unsigned short* Qlo = uu;  uu += (size_t)HQ_ * T_ * D_;
  unsigned short* Khi = uu;  uu += (size_t)HK_ * T_ * D_;
  unsigned short* Klo = uu;  uu += (size_t)HK_ * T_ * D_;
  unsigned short* Vthi = uu; uu += (size_t)HK_ * D_ * T_;
  unsigned short* Vtlo = uu; uu += (size_t)HK_ * D_ * T_;

  // ---- transient: MoE phase (aliases attention transients; conv runs after router) ----
  unsigned short* W1b = (unsigned short*)trans;      // E*I*H
  unsigned short* W3b = W1b + (size_t)NE_ * II_ * H_;
  unsigned short* W2b = W3b + (size_t)NE_ * II_ * H_;

  const int WCNT8 = (NE_ * II_ * H_) / 8;

  hipMemsetAsync(ctrl, 0, 64, stream);  // counts + counts2
  k_rmsnorm_split<<<T_, 256, 0, stream>>>(x, nin_w, Aq);
  k_wsplit<<<2048, 256, 0, stream>>>(qkv_w, Bq, H_, 1536 * H_ / 8);
  k_wsplit<<<2048, 256, 0, stream>>>(o_w, Bo, HQ_ * D_, H_ * HQ_ * D_ / 8);
  k_hgemm<0><<<dim3(1536 / 64, T_ / 128), 256, 0, stream>>>(Aq, Bq, qkvb, nullptr, 1536, 3 * H_);
  k_rope_table<<<T_ * 32 / 256, 256, 0, stream>>>(pos, ct, st);
  k_rope_prep<<<T_, 256, 0, stream>>>(qkvb, ct, st, Qhi, Qlo, Khi, Klo);
  k_vtrans<<<dim3(T_ / 64, HK_), 256, 0, stream>>>(qkvb, Vthi, Vtlo);
  k_attn_mfma<<<dim3(512), 256, 0, stream>>>(Qhi, Qlo, Khi, Klo, Vthi, Vtlo, Ao);
  k_hgemm<1><<<dim3(H_ / 64, T_ / 128), 256, 0, stream>>>(Ao, Bo, resid, x, H_, 3 * HQ_ * D_);
  k_rmsnorm<<<T_, 256, 0, stream>>>(resid, npost_w, h2, h2b);
  k_router<<<T_ / 4, 256, 0, stream>>>(h2, gate_w, topi, topw, counts);
  k_scan<<<1, 64, 0, stream>>>(counts, offsets);
  k_build<<<T_ / 256, 256, 0, stream>>>(topi, topw, offsets, counts2, pairs_ts, pairsw);
  // weight pre-conversion (attention transients are dead now)
  k_conv<<<2048, 256, 0, stream>>>(w1, W1b, WCNT8);
  k_conv<<<2048, 256, 0, stream>>>(w3, W3b, WCNT8);
  k_conv<<<2048, 256, 0, stream>>>(w2, W2b, WCNT8);
  k_moe_up<<<dim3(II_ / 64, T_ / 128, NE_), 256, 0, stream>>>(h2b, W1b, W3b, pairs_ts, offsets, counts, G);
  k_moe_down<<<dim3(H_ / 64, T_ / 128, NE_), 256, 0, stream>>>(G, W2b, pairs_ts, pairsw, offsets, counts, Pbuf);
  k_final<<<T_, 256, 0, stream>>>(resid, Pbuf, nnext_w, out);
}